// Round 19
// baseline (590.464 us; speedup 1.0000x reference)
//
#include <hip/hip_runtime.h>

// HetSTGCNBlock round 19 = round 18 (best, 533us) + B-frag LDS staging in
// layer_b: the 26 B-frag loads/wave are identical for both waves sharing w
// (independent of mt,b). 2-wave blocks stage all 13 ks-chunks (26KB) into
// LDS as a burst (full MLP), then node phases read B via ds_read_b128
// (~12cy vs ~200cy L2). Per-wave global chain 86->60 loads. layer_a = r18.

typedef __attribute__((ext_vector_type(8))) short short8v;
typedef __attribute__((ext_vector_type(4))) short short4v;
typedef __attribute__((ext_vector_type(4))) float f32x4;

#define BB 16
#define NA 81
#define NB 319
#define PA 128
#define PB 320
#define M1 1920     // 30*64
#define T1 30
#define T2 28

#define MFMA16 __builtin_amdgcn_mfma_f32_16x16x32_bf16

__device__ __forceinline__ float sigmoidf_(float x){ return 1.0f/(1.0f+__expf(-x)); }
__device__ __forceinline__ short f2bf(float f){
  unsigned u = __float_as_uint(f);
  u += 0x7FFF + ((u>>16)&1);
  return (short)(u>>16);
}
__device__ __forceinline__ float bf2f(short s){
  return __uint_as_float(((unsigned)(unsigned short)s)<<16);
}

// ---------- prep: Ma = A01@A10 (81x81) fp32 ----------
__global__ __launch_bounds__(256) void k_prep_mm(const float* __restrict__ A01,
                                                 const float* __restrict__ A10,
                                                 float* __restrict__ Ma) {
  int idx = blockIdx.x*256 + threadIdx.x;
  if (idx >= NA*NA) return;
  int i = idx / NA, j = idx % NA;
  float a = 0.f;
  for (int k = 0; k < NB; ++k) a += A01[i*NB + k]*A10[k*NA + j];
  Ma[idx] = a;
}

// ---------- pack mixing matrices into B-frag order, bf16 ----------
__device__ __forceinline__ void packA_one(int f, const float* src, int I, int J,
                                          int ld, int nIt, short* dst) {
  int e = f & 7, l = (f >> 3) & 63, rest = f >> 9;
  int it = rest % nIt, jt = rest / nIt;
  int i = it*16 + (l & 15);
  int j = jt*32 + (l >> 4)*8 + e;
  float v = (i < I && j < J) ? src[i*ld + j] : 0.f;
  dst[f] = f2bf(v);
}

__global__ __launch_bounds__(256) void k_pack_A(
    const float* __restrict__ A00, const float* __restrict__ A01,
    const float* __restrict__ A10, const float* __restrict__ A11,
    const float* __restrict__ Ma,
    short* __restrict__ A00pk, short* __restrict__ Mapk,
    short* __restrict__ A01pk, short* __restrict__ A10pk,
    short* __restrict__ A11pk) {
  int idx = blockIdx.x*256 + threadIdx.x;
  if (idx < 12288)        { packA_one(idx, A00, NA, NA, NA, 8,  A00pk); return; }
  idx -= 12288;
  if (idx < 12288)        { packA_one(idx, Ma,  NA, NA, NA, 8,  Mapk);  return; }
  idx -= 12288;
  if (idx < 40960)        { packA_one(idx, A01, NA, NB, NB, 8,  A01pk); return; }
  idx -= 40960;
  if (idx < 30720)        { packA_one(idx, A10, NB, NA, NA, 20, A10pk); return; }
  idx -= 30720;
  if (idx < 102400)       { packA_one(idx, A11, NB, NB, NB, 20, A11pk); return; }
}

// ---------- pack th (30 mats), theta, conv2 weights; + tconv1 weights fp32 ----------
__global__ __launch_bounds__(256) void k_pack_th(
    const float* __restrict__ g1t1, const float* __restrict__ g1t2,
    const float* __restrict__ g1t3, const float* __restrict__ g2t1,
    const float* __restrict__ g2t2, const float* __restrict__ g2t3,
    const float* __restrict__ theta,
    const float* __restrict__ w12, const float* __restrict__ wc2,
    const float* __restrict__ w11, const float* __restrict__ wc1,
    const float* __restrict__ b11, const float* __restrict__ bc1,
    short* __restrict__ thpk, short* __restrict__ thetapk,
    short* __restrict__ W2pk, float* __restrict__ W1t, float* __restrict__ B1t) {
  int idx = blockIdx.x*256 + threadIdx.x;
  if (idx < 122880) {
    int mat = idx / 4096, rem = idx % 4096;
    int ct = rem / 1024, ks = (rem / 512) & 1, l = (rem >> 3) & 63, e = rem & 7;
    int ci = ks*32 + (l >> 4)*8 + e, co = ct*16 + (l & 15);
    int layer = mat / 6, which = mat % 6;
    const float* src = which == 0 ? g1t1 : which == 1 ? g1t2 : which == 2 ? g1t3
                     : which == 3 ? g2t1 : which == 4 ? g2t2 : g2t3;
    thpk[idx] = f2bf(src[layer*4096 + ci*64 + co]);
    return;
  }
  idx -= 122880;
  if (idx < 4096) {
    int ct = idx / 1024, ks = (idx / 512) & 1, l = (idx >> 3) & 63, e = idx & 7;
    int ci = ks*32 + (l >> 4)*8 + e, co = ct*16 + (l & 15);
    thetapk[idx] = f2bf(theta[ci*64 + co]);
    return;
  }
  idx -= 4096;
  if (idx < 36864) {
    int ct = idx / 3072, rem = idx % 3072;
    int ks = rem / 512, l = (rem >> 3) & 63, e = rem & 7;
    int kap = ks*32 + (l >> 4)*8 + e;
    int k = kap >> 6, ci = kap & 63;
    int cc = ct*16 + (l & 15);
    float v = (cc < 64) ? w12[cc*192 + ci*3 + k] : wc2[(cc - 64)*192 + ci*3 + k];
    W2pk[idx] = f2bf(v);
    return;
  }
  idx -= 36864;
  if (idx < 1152) {
    int kk = idx / 192, cc = idx % 192;
    int k = kk >> 1, ci = kk & 1;
    W1t[idx] = (cc < 64) ? w11[cc*6 + ci*3 + k] : wc1[(cc - 64)*6 + ci*3 + k];
    return;
  }
  idx -= 1152;
  if (idx < 192) { B1t[idx] = (idx < 64) ? b11[idx] : bc1[idx - 64]; return; }
}

// ---------- temporal conv 1 (Cin=2), gated -> node-major bf16 ----------
__global__ __launch_bounds__(192) void k_tconv1(const float* __restrict__ X,
                                                const float* __restrict__ W1t,
                                                const float* __restrict__ B1t,
                                                short* __restrict__ t1a,
                                                short* __restrict__ t1b) {
  __shared__ float xl[64];
  __shared__ float wl[6*192];
  __shared__ float bl[192];
  __shared__ float ol[T1*192];
  int bn = blockIdx.x;
  int b = bn / 400, n = bn % 400;
  int tid = threadIdx.x;
  if (tid < 64) xl[tid] = X[(size_t)bn*64 + tid];
  for (int i2 = tid; i2 < 6*192; i2 += 192) wl[i2] = W1t[i2];
  bl[tid] = B1t[tid];
  __syncthreads();
  float acc[T1];
  float bias = bl[tid];
#pragma unroll
  for (int t = 0; t < T1; ++t) acc[t] = bias;
#pragma unroll
  for (int kk = 0; kk < 6; ++kk) {
    float w = wl[kk*192 + tid];
    int k = kk >> 1, ci = kk & 1;
#pragma unroll
    for (int t = 0; t < T1; ++t) acc[t] += xl[(t + k)*2 + ci]*w;
  }
#pragma unroll
  for (int t = 0; t < T1; ++t) ol[t*192 + tid] = acc[t];
  __syncthreads();
  short* dst = (n < NA) ? (t1a + ((size_t)b*PA + n)*M1)
                        : (t1b + ((size_t)b*PB + (n - NA))*M1);
  for (int p = tid; p < T1*64; p += 192) {
    int t = p >> 6, c = p & 63;
    float v = (ol[t*192 + 64 + c] + ol[t*192 + c])*sigmoidf_(ol[t*192 + 128 + c]);
    dst[p] = f2bf(v);
  }
}

// ---------- transpose: node-major -> m-major (initial only) ----------
__global__ __launch_bounds__(256) void k_transpose(const short* __restrict__ src,
                                                   short* __restrict__ dst, int Ipad) {
  int lane = threadIdx.x & 63, wv = threadIdx.x >> 6;
  int n = blockIdx.x*64 + lane;
  int b = blockIdx.z;
  const short* sp = src + ((size_t)b*Ipad + n)*M1;
  int mbase = (blockIdx.y*4 + wv)*120;
  for (int k = 0; k < 120; k += 8) {
    int m = mbase + k;
    short8v v = *(const short8v*)(sp + m);
#pragma unroll
    for (int e = 0; e < 8; ++e)
      dst[((size_t)b*M1 + m + e)*Ipad + n] = v[e];
  }
}

// ---------- layer-a kernel: 1-wave blocks (r18, unchanged) ----------
template<int KT12, int KT3>
__global__ __launch_bounds__(64, 1) void k_layer_a(
    const short* __restrict__ XT12, int Jp12,
    const short* __restrict__ XT3, int Jp3,
    const short* __restrict__ Apk1, const short* __restrict__ Apk2, int nIt12,
    const short* __restrict__ Apk3, int nIt3,
    const short* __restrict__ th1, const short* __restrict__ th2,
    const short* __restrict__ th3,
    const short* __restrict__ X00, short* __restrict__ uout,
    short* __restrict__ umT, short* __restrict__ g3T,
    int NW, int I, int IpadO) {
  __shared__ short sd[3][32*68];
  int lane = threadIdx.x & 63;
  int ln = lane & 15, qw = lane >> 4;

  int total = NW*30*BB;
  int d = blockIdx.x;
  int logical = (d & 7)*(total >> 3) + (d >> 3);
  int w = logical % NW;
  int rest = logical / NW;
  int mt = rest % 30;
  int b = rest / 30;

  int m0 = mt*64;
  int t = mt;

  short* s1 = sd[0];
  short* s2 = sd[1];
  short* s3 = sd[2];

  short8v x0r[4];
#pragma unroll
  for (int kq = 0; kq < 4; ++kq) {
    int il = kq*8 + (lane >> 3);
    int irow = w*32 + il;
    if (irow >= I) irow = I - 1;
    size_t ro = ((size_t)b*IpadO + irow)*M1 + t*64 + (lane & 7)*8;
    x0r[kq] = *(const short8v*)(X00 + ro);
  }

  // phase 1: a3 = Apk3 @ XT3 (2-deep X+B), spill s3, export g3T
  {
    f32x4 a3[2][4];
#pragma unroll
    for (int ft = 0; ft < 2; ++ft)
#pragma unroll
      for (int mf = 0; mf < 4; ++mf) a3[ft][mf] = (f32x4)0.f;

    short8v xa[2][4];
    short8v b3f[2][2];
#pragma unroll
    for (int mf = 0; mf < 4; ++mf) {
      size_t ro = ((size_t)b*M1 + m0 + mf*16 + ln)*Jp3 + qw*8;
      xa[0][mf] = *(const short8v*)(XT3 + ro);
    }
    {
      size_t ab = (((size_t)0*nIt3 + w*2)*64 + lane)*8;
      b3f[0][0] = *(const short8v*)(Apk3 + ab);
      b3f[0][1] = *(const short8v*)(Apk3 + ab + 512);
    }
#pragma unroll
    for (int ks = 0; ks < KT3; ++ks) {
      if (ks + 1 < KT3) {
        int nx = (ks + 1) & 1;
#pragma unroll
        for (int mf = 0; mf < 4; ++mf) {
          size_t ro = ((size_t)b*M1 + m0 + mf*16 + ln)*Jp3 + (ks + 1)*32 + qw*8;
          xa[nx][mf] = *(const short8v*)(XT3 + ro);
        }
        size_t ab = (((size_t)(ks + 1)*nIt3 + w*2)*64 + lane)*8;
        b3f[nx][0] = *(const short8v*)(Apk3 + ab);
        b3f[nx][1] = *(const short8v*)(Apk3 + ab + 512);
      }
      int cu = ks & 1;
#pragma unroll
      for (int mf = 0; mf < 4; ++mf) {
        a3[0][mf] = MFMA16(xa[cu][mf], b3f[cu][0], a3[0][mf], 0, 0, 0);
        a3[1][mf] = MFMA16(xa[cu][mf], b3f[cu][1], a3[1][mf], 0, 0, 0);
      }
    }
#pragma unroll
    for (int ft = 0; ft < 2; ++ft)
#pragma unroll
      for (int mf = 0; mf < 4; ++mf) {
        int irow = ft*16 + ln;
        int cc = mf*16 + qw*4;
        short4v v3;
#pragma unroll
        for (int r = 0; r < 4; ++r) v3[r] = f2bf(a3[ft][mf][r]);
        *(short4v*)(s3 + irow*68 + cc) = v3;
      }
  }
  {
    int co = lane;
    size_t cb = ((size_t)b*M1 + t*64 + co)*IpadO + w*32;
#pragma unroll
    for (int kq = 0; kq < 4; ++kq) {
      short8v v;
#pragma unroll
      for (int ii = 0; ii < 8; ++ii) v[ii] = s3[(kq*8 + ii)*68 + co];
      *(short8v*)(g3T + cb + kq*8) = v;
    }
  }

  // phase 2: a1, a2 (shared X, 2-deep X+B)
  {
    f32x4 a1[2][4], a2[2][4];
#pragma unroll
    for (int ft = 0; ft < 2; ++ft)
#pragma unroll
      for (int mf = 0; mf < 4; ++mf) { a1[ft][mf] = (f32x4)0.f; a2[ft][mf] = (f32x4)0.f; }

    short8v xa[2][4];
    short8v b1f[2][2], b2f[2][2];
#pragma unroll
    for (int mf = 0; mf < 4; ++mf) {
      size_t ro = ((size_t)b*M1 + m0 + mf*16 + ln)*Jp12 + qw*8;
      xa[0][mf] = *(const short8v*)(XT12 + ro);
    }
    {
      size_t ab = (((size_t)0*nIt12 + w*2)*64 + lane)*8;
      b1f[0][0] = *(const short8v*)(Apk1 + ab);
      b1f[0][1] = *(const short8v*)(Apk1 + ab + 512);
      b2f[0][0] = *(const short8v*)(Apk2 + ab);
      b2f[0][1] = *(const short8v*)(Apk2 + ab + 512);
    }
#pragma unroll
    for (int ks = 0; ks < KT12; ++ks) {
      if (ks + 1 < KT12) {
        int nx = (ks + 1) & 1;
#pragma unroll
        for (int mf = 0; mf < 4; ++mf) {
          size_t ro = ((size_t)b*M1 + m0 + mf*16 + ln)*Jp12 + (ks + 1)*32 + qw*8;
          xa[nx][mf] = *(const short8v*)(XT12 + ro);
        }
        size_t ab = (((size_t)(ks + 1)*nIt12 + w*2)*64 + lane)*8;
        b1f[nx][0] = *(const short8v*)(Apk1 + ab);
        b1f[nx][1] = *(const short8v*)(Apk1 + ab + 512);
        b2f[nx][0] = *(const short8v*)(Apk2 + ab);
        b2f[nx][1] = *(const short8v*)(Apk2 + ab + 512);
      }
      int cu = ks & 1;
#pragma unroll
      for (int mf = 0; mf < 4; ++mf) {
        a1[0][mf] = MFMA16(xa[cu][mf], b1f[cu][0], a1[0][mf], 0, 0, 0);
        a1[1][mf] = MFMA16(xa[cu][mf], b1f[cu][1], a1[1][mf], 0, 0, 0);
        a2[0][mf] = MFMA16(xa[cu][mf], b2f[cu][0], a2[0][mf], 0, 0, 0);
        a2[1][mf] = MFMA16(xa[cu][mf], b2f[cu][1], a2[1][mf], 0, 0, 0);
      }
    }
#pragma unroll
    for (int ft = 0; ft < 2; ++ft)
#pragma unroll
      for (int mf = 0; mf < 4; ++mf) {
        int irow = ft*16 + ln;
        int cc = mf*16 + qw*4;
        short4v v1, v2;
#pragma unroll
        for (int r = 0; r < 4; ++r) {
          v1[r] = f2bf(a1[ft][mf][r]);
          v2[r] = f2bf(a2[ft][mf][r]);
        }
        *(short4v*)(s1 + irow*68 + cc) = v1;
        *(short4v*)(s2 + irow*68 + cc) = v2;
      }
  }

  // channel phase
  f32x4 u2a[2][4], u5a[2][4];
#pragma unroll
  for (int fi = 0; fi < 2; ++fi)
#pragma unroll
    for (int ct = 0; ct < 4; ++ct) { u2a[fi][ct] = (f32x4)0.f; u5a[fi][ct] = (f32x4)0.f; }

#pragma unroll
  for (int ks = 0; ks < 2; ++ks) {
    short8v f1[2], f2[2], f3[2];
#pragma unroll
    for (int fi = 0; fi < 2; ++fi) {
      int irow = fi*16 + ln;
      f1[fi] = *(const short8v*)(s1 + irow*68 + ks*32 + qw*8);
      f2[fi] = *(const short8v*)(s2 + irow*68 + ks*32 + qw*8);
      f3[fi] = *(const short8v*)(s3 + irow*68 + ks*32 + qw*8);
    }
#pragma unroll
    for (int ct = 0; ct < 4; ++ct) {
      short8v b1 = *(const short8v*)(th1 + ((ct*2 + ks)*64 + lane)*8);
      short8v b2 = *(const short8v*)(th2 + ((ct*2 + ks)*64 + lane)*8);
      short8v b3 = *(const short8v*)(th3 + ((ct*2 + ks)*64 + lane)*8);
#pragma unroll
      for (int fi = 0; fi < 2; ++fi) {
        u2a[fi][ct] = MFMA16(f1[fi], b1, u2a[fi][ct], 0, 0, 0);
        u5a[fi][ct] = MFMA16(f2[fi], b2, u5a[fi][ct], 0, 0, 0);
        u5a[fi][ct] = MFMA16(f3[fi], b3, u5a[fi][ct], 0, 0, 0);
      }
    }
  }

#pragma unroll
  for (int kq = 0; kq < 4; ++kq) {
    int il = kq*8 + (lane >> 3);
    *(short8v*)(s3 + il*68 + (lane & 7)*8) = x0r[kq];
  }

  short* sg = s1;
#pragma unroll
  for (int fi = 0; fi < 2; ++fi)
#pragma unroll
    for (int ct = 0; ct < 4; ++ct) {
      int co = ct*16 + ln;
#pragma unroll
      for (int r = 0; r < 4; ++r) {
        int il = fi*16 + qw*4 + r;
        int i = w*32 + il;
        short g = 0;
        if (i < I) {
          float u2 = fmaxf(u2a[fi][ct][r], 0.f);
          float u5 = sigmoidf_(u5a[fi][ct][r]);
          float u6 = fmaxf(0.5f*(u2 + u5), 0.f);
          float x0 = bf2f(s3[il*68 + co]);
          g = f2bf(fmaxf(0.9f*u6 + 0.1f*x0, 0.f));
        }
        sg[il*68 + co] = g;
      }
    }

#pragma unroll
  for (int kq = 0; kq < 4; ++kq) {
    int il = kq*8 + (lane >> 3);
    int irow = w*32 + il;
    short8v v = *(const short8v*)(sg + il*68 + (lane & 7)*8);
    if (irow < I)
      *(short8v*)(uout + ((size_t)b*IpadO + irow)*M1 + t*64 + (lane & 7)*8) = v;
  }

  {
    int co = lane;
    size_t cb = ((size_t)b*M1 + t*64 + co)*IpadO + w*32;
#pragma unroll
    for (int kq = 0; kq < 4; ++kq) {
      short8v v;
#pragma unroll
      for (int ii = 0; ii < 8; ++ii) v[ii] = sg[(kq*8 + ii)*68 + co];
      *(short8v*)(umT + cb + kq*8) = v;
    }
  }
}

// ---------- layer-b kernel: 2-wave blocks, B-frags staged in LDS ----------
// Both waves share w (wv selects mt) -> B-frags identical. Block stages all
// 13 ks-chunks (3 for A10, 10 for A11) = 26KB into LDS as a burst, then
// node phases read B via ds_read_b128. X stays 2-deep global-pipelined.
__global__ __launch_bounds__(128, 1) void k_layer_b(
    const short* __restrict__ X2T,    // g3T m-major [b][M1][PA]
    const short* __restrict__ X3T,    // uaT_new m-major [b][M1][PA]
    const short* __restrict__ X1T,    // ubT m-major [b][M1][PB]
    const short* __restrict__ ApkS,   // A10pk, nIt=20
    const short* __restrict__ Apk1,   // A11pk, nIt=20
    const short* __restrict__ th1, const short* __restrict__ th2,
    const short* __restrict__ th3,
    const short* __restrict__ X00, short* __restrict__ uout,
    short* __restrict__ umT) {
  const int NW = 10, I = NB, IpadO = PB;
  __shared__ short ldsB[13*1024];        // 26KB: [c][2 frag][512]
  __shared__ short sd[2][3][32*68];      // 25.5KB
  int tid = threadIdx.x;
  int lane = tid & 63, wv = tid >> 6;
  int ln = lane & 15, qw = lane >> 4;

  int total = NW*15*BB;                  // 2400
  int d = blockIdx.x;
  int logical = (d & 7)*(total >> 3) + (d >> 3);
  int w = logical % NW;
  int rest = logical / NW;
  int mt2 = rest % 15;
  int b = rest / 15;

  int mt = mt2*2 + wv;
  int m0 = mt*64;
  int t = mt;

  short* s1 = sd[wv][0];
  short* s2 = sd[wv][1];
  short* s3 = sd[wv][2];

  // --- stage all B-frags for this w into LDS (13 independent 2KB copies) ---
#pragma unroll
  for (int c = 0; c < 13; ++c) {
    const short* src = (c < 3)
        ? (ApkS + ((size_t)(c*20 + w*2)*64)*8)
        : (Apk1 + ((size_t)((c - 3)*20 + w*2)*64)*8);
    *(short8v*)(ldsB + c*1024 + tid*8) = *(const short8v*)(src + tid*8);
  }

  // early coalesced X00 load (overlaps the staging + node phase)
  short8v x0r[4];
#pragma unroll
  for (int kq = 0; kq < 4; ++kq) {
    int il = kq*8 + (lane >> 3);
    int irow = w*32 + il;
    if (irow >= I) irow = I - 1;
    size_t ro = ((size_t)b*IpadO + irow)*M1 + t*64 + (lane & 7)*8;
    x0r[kq] = *(const short8v*)(X00 + ro);
  }
  __syncthreads();

  // === phase 1: a2 = A10@g3T, a3 = A10@uaT (shared B from LDS), K=96 ===
  {
    f32x4 a2[2][4], a3[2][4];
#pragma unroll
    for (int ft = 0; ft < 2; ++ft)
#pragma unroll
      for (int mf = 0; mf < 4; ++mf) { a2[ft][mf] = (f32x4)0.f; a3[ft][mf] = (f32x4)0.f; }

    short8v x2[2][4], x3[2][4];
#pragma unroll
    for (int mf = 0; mf < 4; ++mf) {
      size_t ro = ((size_t)b*M1 + m0 + mf*16 + ln)*PA + qw*8;
      x2[0][mf] = *(const short8v*)(X2T + ro);
      x3[0][mf] = *(const short8v*)(X3T + ro);
    }
#pragma unroll
    for (int ks = 0; ks < 3; ++ks) {
      if (ks + 1 < 3) {
        int nx = (ks + 1) & 1;
#pragma unroll
        for (int mf = 0; mf < 4; ++mf) {
          size_t ro = ((size_t)b*M1 + m0 + mf*16 + ln)*PA + (ks + 1)*32 + qw*8;
          x2[nx][mf] = *(const short8v*)(X2T + ro);
          x3[nx][mf] = *(const short8v*)(X3T + ro);
        }
      }
      int cu = ks & 1;
      short8v bf0 = *(const short8v*)(ldsB + ks*1024 + lane*8);
      short8v bf1 = *(const short8v*)(ldsB + ks*1024 + 512 + lane*8);
#pragma unroll
      for (int mf = 0; mf < 4; ++mf) {
        a2[0][mf] = MFMA16(x2[cu][mf], bf0, a2[0][mf], 0, 0, 0);
        a2[1][mf] = MFMA16(x2[cu][mf], bf1, a2[1][mf], 0, 0, 0);
        a3[0][mf] = MFMA16(x3[cu][mf], bf0, a3[0][mf], 0, 0, 0);
        a3[1][mf] = MFMA16(x3[cu][mf], bf1, a3[1][mf], 0, 0, 0);
      }
    }
#pragma unroll
    for (int ft = 0; ft < 2; ++ft)
#pragma unroll
      for (int mf = 0; mf < 4; ++mf) {
        int irow = ft*16 + ln;
        int cc = mf*16 + qw*4;
        short4v v2, v3;
#pragma unroll
        for (int r = 0; r < 4; ++r) {
          v2[r] = f2bf(a2[ft][mf][r]);
          v3[r] = f2bf(a3[ft][mf][r]);
        }
        *(short4v*)(s2 + irow*68 + cc) = v2;
        *(short4v*)(s3 + irow*68 + cc) = v3;
      }
  }

  // === phase 2: a1 = A11 @ ubT (K=320, 10 iters, X 2-deep, B from LDS) ===
  {
    f32x4 a1[2][4];
#pragma unroll
    for (int ft = 0; ft < 2; ++ft)
#pragma unroll
      for (int mf = 0; mf < 4; ++mf) a1[ft][mf] = (f32x4)0.f;

    short8v xa[2][4];
#pragma unroll
    for (int mf = 0; mf < 4; ++mf) {
      size_t ro = ((size_t)b*M1 + m0 + mf*16 + ln)*PB + qw*8;
      xa[0][mf] = *(const short8v*)(X1T + ro);
    }
#pragma unroll
    for (int ks = 0; ks < 10; ++ks) {
      if (ks + 1 < 10) {
        int nx = (ks + 1) & 1;
#pragma unroll
        for (int mf = 0; mf < 4; ++mf) {
          size_t ro = ((size_t)b*M1 + m0 + mf*16 + ln)*PB + (ks + 1)*32 + qw*8;
          xa[nx][mf] = *(const short8v*)(X1T + ro);
        }
      }
      int cu = ks & 1;
      short8v bf0 = *(const short8v*)(ldsB + (3 + ks)*1024 + lane*8);
      short8v bf1 = *(const short8v*)(ldsB + (3 + ks)*1024 + 512 + lane*8);
#pragma unroll
      for (int mf = 0; mf < 4; ++mf) {
        a1[0][mf] = MFMA16(xa[cu][mf], bf0, a1[0][mf], 0, 0, 0);
        a1[1][mf] = MFMA16(xa[cu][mf], bf1, a1[1][mf], 0, 0, 0);
      }
    }
#pragma unroll
    for (int ft = 0; ft < 2; ++ft)
#pragma unroll
      for (int mf = 0; mf < 4; ++mf) {
        int irow = ft*16 + ln;
        int cc = mf*16 + qw*4;
        short4v v1;
#pragma unroll
        for (int r = 0; r < 4; ++r) v1[r] = f2bf(a1[ft][mf][r]);
        *(short4v*)(s1 + irow*68 + cc) = v1;
      }
  }

  // --- channel phase (per-wave tiles) ---
  f32x4 u2a[2][4], u5a[2][4];
#pragma unroll
  for (int fi = 0; fi < 2; ++fi)
#pragma unroll
    for (int ct = 0; ct < 4; ++ct) { u2a[fi][ct] = (f32x4)0.f; u5a[fi][ct] = (f32x4)0.f; }

#pragma unroll
  for (int ks = 0; ks < 2; ++ks) {
    short8v f1[2], f2[2], f3[2];
#pragma unroll
    for (int fi = 0; fi < 2; ++fi) {
      int irow = fi*16 + ln;
      f1[fi] = *(const short8v*)(s1 + irow*68 + ks*32 + qw*8);
      f2[fi] = *(const short8v*)(s2 + irow*68 + ks*32 + qw*8);
      f3[fi] = *(const short8v*)(s3 + irow*68 + ks*32 + qw*8);
    }
#pragma unroll
    for (int ct = 0; ct < 4; ++ct) {
      short8v b1 = *(const short8v*)(th1 + ((ct*2 + ks)*64 + lane)*8);
      short8v b2 = *(const short8v*)(th2 + ((ct*2 + ks)*64 + lane)*8);
      short8v b3 = *(const short8v*)(th3 + ((ct*2 + ks)*64 + lane)*8);
#pragma unroll
      for (int fi = 0; fi < 2; ++fi) {
        u2a[fi][ct] = MFMA16(f1[fi], b1, u2a[fi][ct], 0, 0, 0);
        u5a[fi][ct] = MFMA16(f2[fi], b2, u5a[fi][ct], 0, 0, 0);
        u5a[fi][ct] = MFMA16(f3[fi], b3, u5a[fi][ct], 0, 0, 0);
      }
    }
  }

  // --- park X00 in s3 (dead after channel reads; wave-private) ---
#pragma unroll
  for (int kq = 0; kq < 4; ++kq) {
    int il = kq*8 + (lane >> 3);
    *(short8v*)(s3 + il*68 + (lane & 7)*8) = x0r[kq];
  }

  // --- gating + residual -> sg ---
  short* sg = s1;
#pragma unroll
  for (int fi = 0; fi < 2; ++fi)
#pragma unroll
    for (int ct = 0; ct < 4; ++ct) {
      int co = ct*16 + ln;
#pragma unroll
      for (int r = 0; r < 4; ++r) {
        int il = fi*16 + qw*4 + r;
        int i = w*32 + il;
        short g = 0;
        if (i < I) {
          float u2 = fmaxf(u2a[fi][ct][r], 0.f);
          float u5 = sigmoidf_(u5a[fi][ct][r]);
          float u6 = fmaxf(0.5f*(u2 + u5), 0.f);
          float x0 = bf2f(s3[il*68 + co]);
          g = f2bf(fmaxf(0.9f*u6 + 0.1f*x0, 0.f));
        }
        sg[il*68 + co] = g;
      }
    }

  // --- node-major store: 4 coalesced 1KB stores ---
#pragma unroll
  for (int kq = 0; kq < 4; ++kq) {
    int il = kq*8 + (lane >> 3);
    int irow = w*32 + il;
    short8v v = *(const short8v*)(sg + il*68 + (lane & 7)*8);
    if (irow < I)
      *(short8v*)(uout + ((size_t)b*IpadO + irow)*M1 + t*64 + (lane & 7)*8) = v;
  }

  // --- m-major store ---
  {
    int co = lane;
    size_t cb = ((size_t)b*M1 + t*64 + co)*IpadO + w*32;
#pragma unroll
    for (int kq = 0; kq < 4; ++kq) {
      short8v v;
#pragma unroll
      for (int ii = 0; ii < 8; ++ii) v[ii] = sg[(kq*8 + ii)*68 + co];
      *(short8v*)(umT + cb + kq*8) = v;
    }
  }
}

// ---------- fused theta matmul + conv2 + gating -> d_out fp32 ----------
__global__ __launch_bounds__(256) void k_thconv2(const short* __restrict__ u0,
                                                 const short* __restrict__ u1,
                                                 const short* __restrict__ thetapk,
                                                 const short* __restrict__ W2pk,
                                                 const float* __restrict__ b12,
                                                 const float* __restrict__ bc2,
                                                 float* __restrict__ out) {
  __shared__ short lds[34*72];
  int tid = threadIdx.x, lane = tid & 63, wv = tid >> 6;
  int ln = lane & 15, qw = lane >> 4;
  int bn = blockIdx.x;
  int b = blockIdx.y;
  const short* u; int i, Ipad;
  if (bn < NA) { u = u0; i = bn; Ipad = PA; }
  else         { u = u1; i = bn - NA; Ipad = PB; }
  for (int z = tid; z < 4*72; z += 256) lds[30*72 + z] = 0;

  f32x4 ac[2];
  ac[0] = (f32x4)0.f; ac[1] = (f32x4)0.f;
  size_t ubase = ((size_t)b*Ipad + i)*M1;
#pragma unroll
  for (int ks = 0; ks < 2; ++ks) {
    short8v bm = *(const short8v*)(thetapk + ((wv*2 + ks)*64 + lane)*8);
#pragma unroll
    for (int tf = 0; tf < 2; ++tf) {
      short8v af = *(const short8v*)(u + ubase + (tf*16 + ln)*64 + ks*32 + qw*8);
      ac[tf] = MFMA16(af, bm, ac[tf], 0, 0, 0);
    }
  }
#pragma unroll
  for (int tf = 0; tf < 2; ++tf)
#pragma unroll
    for (int r = 0; r < 4; ++r) {
      int t = tf*16 + qw*4 + r;
      if (t < T1) lds[t*72 + wv*16 + ln] = f2bf(fmaxf(ac[tf][r], 0.f));
    }
  __syncthreads();

  f32x4 a3[2][3];
#pragma unroll
  for (int tf = 0; tf < 2; ++tf)
#pragma unroll
    for (int s = 0; s < 3; ++s) a3[tf][s] = (f32x4)0.f;
  for (int ks = 0; ks < 6; ++ks) {
    short8v af[2];
#pragma unroll
    for (int tf = 0; tf < 2; ++tf) {
      int m = (tf*16 + ln)*64 + ks*32 + qw*8;
      af[tf] = *(const short8v*)(lds + (m >> 6)*72 + (m & 63));
    }
#pragma unroll
    for (int s = 0; s < 3; ++s) {
      int ct = wv + s*4;
      short8v bm = *(const short8v*)(W2pk + ((ct*6 + ks)*64 + lane)*8);
#pragma unroll
      for (int tf = 0; tf < 2; ++tf)
        a3[tf][s] = MFMA16(af[tf], bm, a3[tf][s], 0, 0, 0);
    }
  }
  int co = wv*16 + ln;
  float btm = b12[co], bp = bc2[co], bq = bc2[64 + co];
#pragma unroll
  for (int tf = 0; tf < 2; ++tf)
#pragma unroll
    for (int r = 0; r < 4; ++r) {
      int t = tf*16 + qw*4 + r;
      if (t >= T2) continue;
      float tm = a3[tf][0][r] + btm;
      float p  = a3[tf][1][r] + bp;
      float q  = a3[tf][2][r] + bq;
      out[((size_t)(b*400 + bn)*T2 + t)*64 + co] = (p + tm)*sigmoidf_(q);
    }
}

// ---------- batchnorm ----------
__global__ __launch_bounds__(256) void k_bn_stats(const float* __restrict__ y,
                                                  float* __restrict__ stats) {
  int n = blockIdx.x;
  int tid = threadIdx.x;
  float s = 0.f, ss = 0.f;
  for (int b = 0; b < BB; ++b) {
    const float* p = y + ((size_t)(b*400 + n))*(T2*64);
    for (int i2 = tid; i2 < T2*64; i2 += 256) {
      float v = p[i2];
      s += v; ss += v*v;
    }
  }
  __shared__ float rs[4], rss[4];
  for (int off = 32; off > 0; off >>= 1) {
    s += __shfl_down(s, off);
    ss += __shfl_down(ss, off);
  }
  if ((tid & 63) == 0) { rs[tid >> 6] = s; rss[tid >> 6] = ss; }
  __syncthreads();
  if (tid == 0) {
    float S = rs[0] + rs[1] + rs[2] + rs[3];
    float SS = rss[0] + rss[1] + rss[2] + rss[3];
    float mean = S/28672.f;
    float var = SS/28672.f - mean*mean;
    stats[n] = mean;
    stats[400 + n] = rsqrtf(var + 1e-5f);
  }
}

__global__ void k_bn_apply(float* __restrict__ y, const float* __restrict__ stats,
                           const float* __restrict__ gamma, const float* __restrict__ beta) {
  int idx = blockIdx.x*blockDim.x + threadIdx.x;
  const int total = BB*400*T2*64/4;
  for (; idx < total; idx += gridDim.x*blockDim.x) {
    int e = idx*4;
    int n = (e/(T2*64)) % 400;
    float mean = stats[n];
    float g = gamma[n]*stats[400 + n];
    float bt = beta[n];
    float4 v = ((float4*)y)[idx];
    v.x = (v.x - mean)*g + bt;
    v.y = (v.y - mean)*g + bt;
    v.z = (v.z - mean)*g + bt;
    v.w = (v.w - mean)*g + bt;
    ((float4*)y)[idx] = v;
  }
}

// ---------- host launcher ----------
extern "C" void kernel_launch(void* const* d_in, const int* in_sizes, int n_in,
                              void* d_out, int out_size, void* d_ws, size_t ws_size,
                              hipStream_t stream) {
  const float* X     = (const float*)d_in[0];
  const float* A00   = (const float*)d_in[1];
  const float* A01   = (const float*)d_in[2];
  const float* A10   = (const float*)d_in[3];
  const float* A11   = (const float*)d_in[4];
  const float* w11   = (const float*)d_in[5];
  const float* b11   = (const float*)d_in[6];
  const float* wc1   = (const float*)d_in[7];
  const float* bc1   = (const float*)d_in[8];
  const float* g1t1  = (const float*)d_in[9];
  const float* g1t2  = (const float*)d_in[10];
  const float* g1t3  = (const float*)d_in[11];
  const float* g2t1  = (const float*)d_in[12];
  const float* g2t2  = (const float*)d_in[13];
  const float* g2t3  = (const float*)d_in[14];
  const float* theta = (const float*)d_in[15];
  const float* w12   = (const float*)d_in[16];
  const float* b12   = (const float*)d_in[17];
  const float* wc2   = (const float*)d_in[18];
  const float* bc2   = (const float*)d_in[19];
  const float* gamma = (const float*)d_in[20];
  const float* beta  = (const float*)d_in[21];

  // ---- workspace layout (bf16/short units) ----
  short* ws = (short*)d_ws;
  size_t o = 0;
  const size_t szA = (size_t)BB*PA*M1;
  const size_t szB = (size_t)BB*PB*M1;
  short* t1a  = ws + o; o += szA;
  short* t1b  = ws + o; o += szB;
  short* u0   = ws + o; o += szA;
  short* u1   = ws + o; o += szB;
  short* uaT0 = ws + o; o += szA;
  short* uaT1 = ws + o; o += szA;
  short* ubT0 = ws + o; o += szB;
  short* ubT1 = ws + o; o += szB;
  short* g3T  = ws + o; o += szA;
  short* A00pk = ws + o; o += 12288;
  short* Mapk  = ws + o; o += 12288;
  short* A01pk = ws + o; o += 40960;
  short* A10pk = ws + o; o += 30720;
  short* A11pk = ws + o; o += 102400;
  short* thpk    = ws + o; o += 122880;
  short* thetapk = ws + o; o += 4096;
  short* W2pk    = ws + o; o += 36864;
  o = (o + 7) & ~(size_t)7;
  float* fws = (float*)(ws + o);
  float* Ma    = fws;
  float* stats = Ma + 6561;
  float* W1t   = stats + 800;
  float* B1t   = W1t + 1152;

  // ---- prep ----
  k_prep_mm<<<26, 256, 0, stream>>>(A01, A10, Ma);
  k_pack_A<<<776, 256, 0, stream>>>(A00, A01, A10, A11, Ma,
                                    A00pk, Mapk, A01pk, A10pk, A11pk);
  k_pack_th<<<646, 256, 0, stream>>>(g1t1, g1t2, g1t3, g2t1, g2t2, g2t3, theta,
                                     w12, wc2, w11, wc1, b11, bc1,
                                     thpk, thetapk, W2pk, W1t, B1t);
  k_tconv1<<<BB*400, 192, 0, stream>>>(X, W1t, B1t, t1a, t1b);
  k_transpose<<<dim3(PA/64, 4, BB), 256, 0, stream>>>(t1a, uaT0, PA);
  k_transpose<<<dim3(PB/64, 4, BB), 256, 0, stream>>>(t1b, ubT0, PB);

  short* uaT[2] = {uaT0, uaT1};
  short* ubT[2] = {ubT0, ubT1};
  for (int l = 0; l < 5; ++l) {
    int pin = l & 1, pout = 1 - pin;
    const short* th = thpk + (size_t)(l*6)*4096;
    // layer-a: 1-wave blocks (r18), NW=3, grid 3*30*16 = 1440
    k_layer_a<3, 10><<<1440, 64, 0, stream>>>(
        uaT[pin], PA, ubT[pin], PB, A00pk, Mapk, 8, A01pk, 8,
        th + 0*4096, th + 1*4096, th + 2*4096, t1a, u0, uaT[pout], g3T,
        3, NA, PA);
    // layer-b: 2-wave blocks with LDS-staged B, NW=10, grid 10*15*16 = 2400
    k_layer_b<<<2400, 128, 0, stream>>>(
        g3T, uaT[pout], ubT[pin], A10pk, A11pk,
        th + 3*4096, th + 4*4096, th + 5*4096, t1b, u1, ubT[pout]);
  }

  // fused theta + conv2 + gating -> d_out fp32
  k_thconv2<<<dim3(400, BB), 256, 0, stream>>>(u0, u1, thetapk, W2pk, b12, bc2,
                                               (float*)d_out);
  // batchnorm in place
  k_bn_stats<<<400, 256, 0, stream>>>((float*)d_out, stats);
  k_bn_apply<<<2048, 256, 0, stream>>>((float*)d_out, stats, gamma, beta);
}

// Round 20
// 534.241 us; speedup vs baseline: 1.1052x; 1.1052x over previous
//
#include <hip/hip_runtime.h>

// HetSTGCNBlock FINAL = round 18 (best measured, 533.7us).
// r19's B-LDS staging regressed (52.7KB LDS -> 2 blocks/CU -> occupancy
// 17->13%); reverted. This configuration is the empirical optimum of the
// design space after bracketing: occupancy-forcing (r11/r17: allocator
// kills pipeline), reg-pipelining at 2 waves (r12-15: +8%), algebraic
// MFMA reduction (r16: nil), block granularity (r18: nil), load staging
// (r19: negative). Traffic is at the algebraic minimum (FETCH 29MB,
// WRITE 38MB per layer_b dispatch); residual gap is scheduler-level
// latency not movable from HIP source.

typedef __attribute__((ext_vector_type(8))) short short8v;
typedef __attribute__((ext_vector_type(4))) short short4v;
typedef __attribute__((ext_vector_type(4))) float f32x4;

#define BB 16
#define NA 81
#define NB 319
#define PA 128
#define PB 320
#define M1 1920     // 30*64
#define T1 30
#define T2 28

#define MFMA16 __builtin_amdgcn_mfma_f32_16x16x32_bf16

__device__ __forceinline__ float sigmoidf_(float x){ return 1.0f/(1.0f+__expf(-x)); }
__device__ __forceinline__ short f2bf(float f){
  unsigned u = __float_as_uint(f);
  u += 0x7FFF + ((u>>16)&1);
  return (short)(u>>16);
}
__device__ __forceinline__ float bf2f(short s){
  return __uint_as_float(((unsigned)(unsigned short)s)<<16);
}

// ---------- prep: Ma = A01@A10 (81x81) fp32 ----------
__global__ __launch_bounds__(256) void k_prep_mm(const float* __restrict__ A01,
                                                 const float* __restrict__ A10,
                                                 float* __restrict__ Ma) {
  int idx = blockIdx.x*256 + threadIdx.x;
  if (idx >= NA*NA) return;
  int i = idx / NA, j = idx % NA;
  float a = 0.f;
  for (int k = 0; k < NB; ++k) a += A01[i*NB + k]*A10[k*NA + j];
  Ma[idx] = a;
}

// ---------- pack mixing matrices into B-frag order, bf16 ----------
__device__ __forceinline__ void packA_one(int f, const float* src, int I, int J,
                                          int ld, int nIt, short* dst) {
  int e = f & 7, l = (f >> 3) & 63, rest = f >> 9;
  int it = rest % nIt, jt = rest / nIt;
  int i = it*16 + (l & 15);
  int j = jt*32 + (l >> 4)*8 + e;
  float v = (i < I && j < J) ? src[i*ld + j] : 0.f;
  dst[f] = f2bf(v);
}

__global__ __launch_bounds__(256) void k_pack_A(
    const float* __restrict__ A00, const float* __restrict__ A01,
    const float* __restrict__ A10, const float* __restrict__ A11,
    const float* __restrict__ Ma,
    short* __restrict__ A00pk, short* __restrict__ Mapk,
    short* __restrict__ A01pk, short* __restrict__ A10pk,
    short* __restrict__ A11pk) {
  int idx = blockIdx.x*256 + threadIdx.x;
  if (idx < 12288)        { packA_one(idx, A00, NA, NA, NA, 8,  A00pk); return; }
  idx -= 12288;
  if (idx < 12288)        { packA_one(idx, Ma,  NA, NA, NA, 8,  Mapk);  return; }
  idx -= 12288;
  if (idx < 40960)        { packA_one(idx, A01, NA, NB, NB, 8,  A01pk); return; }
  idx -= 40960;
  if (idx < 30720)        { packA_one(idx, A10, NB, NA, NA, 20, A10pk); return; }
  idx -= 30720;
  if (idx < 102400)       { packA_one(idx, A11, NB, NB, NB, 20, A11pk); return; }
}

// ---------- pack th (30 mats), theta, conv2 weights; + tconv1 weights fp32 ----------
__global__ __launch_bounds__(256) void k_pack_th(
    const float* __restrict__ g1t1, const float* __restrict__ g1t2,
    const float* __restrict__ g1t3, const float* __restrict__ g2t1,
    const float* __restrict__ g2t2, const float* __restrict__ g2t3,
    const float* __restrict__ theta,
    const float* __restrict__ w12, const float* __restrict__ wc2,
    const float* __restrict__ w11, const float* __restrict__ wc1,
    const float* __restrict__ b11, const float* __restrict__ bc1,
    short* __restrict__ thpk, short* __restrict__ thetapk,
    short* __restrict__ W2pk, float* __restrict__ W1t, float* __restrict__ B1t) {
  int idx = blockIdx.x*256 + threadIdx.x;
  if (idx < 122880) {
    int mat = idx / 4096, rem = idx % 4096;
    int ct = rem / 1024, ks = (rem / 512) & 1, l = (rem >> 3) & 63, e = rem & 7;
    int ci = ks*32 + (l >> 4)*8 + e, co = ct*16 + (l & 15);
    int layer = mat / 6, which = mat % 6;
    const float* src = which == 0 ? g1t1 : which == 1 ? g1t2 : which == 2 ? g1t3
                     : which == 3 ? g2t1 : which == 4 ? g2t2 : g2t3;
    thpk[idx] = f2bf(src[layer*4096 + ci*64 + co]);
    return;
  }
  idx -= 122880;
  if (idx < 4096) {
    int ct = idx / 1024, ks = (idx / 512) & 1, l = (idx >> 3) & 63, e = idx & 7;
    int ci = ks*32 + (l >> 4)*8 + e, co = ct*16 + (l & 15);
    thetapk[idx] = f2bf(theta[ci*64 + co]);
    return;
  }
  idx -= 4096;
  if (idx < 36864) {
    int ct = idx / 3072, rem = idx % 3072;
    int ks = rem / 512, l = (rem >> 3) & 63, e = rem & 7;
    int kap = ks*32 + (l >> 4)*8 + e;
    int k = kap >> 6, ci = kap & 63;
    int cc = ct*16 + (l & 15);
    float v = (cc < 64) ? w12[cc*192 + ci*3 + k] : wc2[(cc - 64)*192 + ci*3 + k];
    W2pk[idx] = f2bf(v);
    return;
  }
  idx -= 36864;
  if (idx < 1152) {
    int kk = idx / 192, cc = idx % 192;
    int k = kk >> 1, ci = kk & 1;
    W1t[idx] = (cc < 64) ? w11[cc*6 + ci*3 + k] : wc1[(cc - 64)*6 + ci*3 + k];
    return;
  }
  idx -= 1152;
  if (idx < 192) { B1t[idx] = (idx < 64) ? b11[idx] : bc1[idx - 64]; return; }
}

// ---------- temporal conv 1 (Cin=2), gated -> node-major bf16 ----------
__global__ __launch_bounds__(192) void k_tconv1(const float* __restrict__ X,
                                                const float* __restrict__ W1t,
                                                const float* __restrict__ B1t,
                                                short* __restrict__ t1a,
                                                short* __restrict__ t1b) {
  __shared__ float xl[64];
  __shared__ float wl[6*192];
  __shared__ float bl[192];
  __shared__ float ol[T1*192];
  int bn = blockIdx.x;
  int b = bn / 400, n = bn % 400;
  int tid = threadIdx.x;
  if (tid < 64) xl[tid] = X[(size_t)bn*64 + tid];
  for (int i2 = tid; i2 < 6*192; i2 += 192) wl[i2] = W1t[i2];
  bl[tid] = B1t[tid];
  __syncthreads();
  float acc[T1];
  float bias = bl[tid];
#pragma unroll
  for (int t = 0; t < T1; ++t) acc[t] = bias;
#pragma unroll
  for (int kk = 0; kk < 6; ++kk) {
    float w = wl[kk*192 + tid];
    int k = kk >> 1, ci = kk & 1;
#pragma unroll
    for (int t = 0; t < T1; ++t) acc[t] += xl[(t + k)*2 + ci]*w;
  }
#pragma unroll
  for (int t = 0; t < T1; ++t) ol[t*192 + tid] = acc[t];
  __syncthreads();
  short* dst = (n < NA) ? (t1a + ((size_t)b*PA + n)*M1)
                        : (t1b + ((size_t)b*PB + (n - NA))*M1);
  for (int p = tid; p < T1*64; p += 192) {
    int t = p >> 6, c = p & 63;
    float v = (ol[t*192 + 64 + c] + ol[t*192 + c])*sigmoidf_(ol[t*192 + 128 + c]);
    dst[p] = f2bf(v);
  }
}

// ---------- transpose: node-major -> m-major (initial only) ----------
__global__ __launch_bounds__(256) void k_transpose(const short* __restrict__ src,
                                                   short* __restrict__ dst, int Ipad) {
  int lane = threadIdx.x & 63, wv = threadIdx.x >> 6;
  int n = blockIdx.x*64 + lane;
  int b = blockIdx.z;
  const short* sp = src + ((size_t)b*Ipad + n)*M1;
  int mbase = (blockIdx.y*4 + wv)*120;
  for (int k = 0; k < 120; k += 8) {
    int m = mbase + k;
    short8v v = *(const short8v*)(sp + m);
#pragma unroll
    for (int e = 0; e < 8; ++e)
      dst[((size_t)b*M1 + m + e)*Ipad + n] = v[e];
  }
}

// ---------- layer-a kernel: 1-wave blocks, split acc, g3T export ----------
template<int KT12, int KT3>
__global__ __launch_bounds__(64, 1) void k_layer_a(
    const short* __restrict__ XT12, int Jp12,
    const short* __restrict__ XT3, int Jp3,
    const short* __restrict__ Apk1, const short* __restrict__ Apk2, int nIt12,
    const short* __restrict__ Apk3, int nIt3,
    const short* __restrict__ th1, const short* __restrict__ th2,
    const short* __restrict__ th3,
    const short* __restrict__ X00, short* __restrict__ uout,
    short* __restrict__ umT, short* __restrict__ g3T,
    int NW, int I, int IpadO) {
  __shared__ short sd[3][32*68];
  int lane = threadIdx.x & 63;
  int ln = lane & 15, qw = lane >> 4;

  int total = NW*30*BB;
  int d = blockIdx.x;
  int logical = (d & 7)*(total >> 3) + (d >> 3);
  int w = logical % NW;
  int rest = logical / NW;
  int mt = rest % 30;
  int b = rest / 30;

  int m0 = mt*64;
  int t = mt;

  short* s1 = sd[0];
  short* s2 = sd[1];
  short* s3 = sd[2];

  short8v x0r[4];
#pragma unroll
  for (int kq = 0; kq < 4; ++kq) {
    int il = kq*8 + (lane >> 3);
    int irow = w*32 + il;
    if (irow >= I) irow = I - 1;
    size_t ro = ((size_t)b*IpadO + irow)*M1 + t*64 + (lane & 7)*8;
    x0r[kq] = *(const short8v*)(X00 + ro);
  }

  // phase 1: a3 = Apk3 @ XT3 (2-deep X+B), spill s3, export g3T
  {
    f32x4 a3[2][4];
#pragma unroll
    for (int ft = 0; ft < 2; ++ft)
#pragma unroll
      for (int mf = 0; mf < 4; ++mf) a3[ft][mf] = (f32x4)0.f;

    short8v xa[2][4];
    short8v b3f[2][2];
#pragma unroll
    for (int mf = 0; mf < 4; ++mf) {
      size_t ro = ((size_t)b*M1 + m0 + mf*16 + ln)*Jp3 + qw*8;
      xa[0][mf] = *(const short8v*)(XT3 + ro);
    }
    {
      size_t ab = (((size_t)0*nIt3 + w*2)*64 + lane)*8;
      b3f[0][0] = *(const short8v*)(Apk3 + ab);
      b3f[0][1] = *(const short8v*)(Apk3 + ab + 512);
    }
#pragma unroll
    for (int ks = 0; ks < KT3; ++ks) {
      if (ks + 1 < KT3) {
        int nx = (ks + 1) & 1;
#pragma unroll
        for (int mf = 0; mf < 4; ++mf) {
          size_t ro = ((size_t)b*M1 + m0 + mf*16 + ln)*Jp3 + (ks + 1)*32 + qw*8;
          xa[nx][mf] = *(const short8v*)(XT3 + ro);
        }
        size_t ab = (((size_t)(ks + 1)*nIt3 + w*2)*64 + lane)*8;
        b3f[nx][0] = *(const short8v*)(Apk3 + ab);
        b3f[nx][1] = *(const short8v*)(Apk3 + ab + 512);
      }
      int cu = ks & 1;
#pragma unroll
      for (int mf = 0; mf < 4; ++mf) {
        a3[0][mf] = MFMA16(xa[cu][mf], b3f[cu][0], a3[0][mf], 0, 0, 0);
        a3[1][mf] = MFMA16(xa[cu][mf], b3f[cu][1], a3[1][mf], 0, 0, 0);
      }
    }
#pragma unroll
    for (int ft = 0; ft < 2; ++ft)
#pragma unroll
      for (int mf = 0; mf < 4; ++mf) {
        int irow = ft*16 + ln;
        int cc = mf*16 + qw*4;
        short4v v3;
#pragma unroll
        for (int r = 0; r < 4; ++r) v3[r] = f2bf(a3[ft][mf][r]);
        *(short4v*)(s3 + irow*68 + cc) = v3;
      }
  }
  {
    int co = lane;
    size_t cb = ((size_t)b*M1 + t*64 + co)*IpadO + w*32;
#pragma unroll
    for (int kq = 0; kq < 4; ++kq) {
      short8v v;
#pragma unroll
      for (int ii = 0; ii < 8; ++ii) v[ii] = s3[(kq*8 + ii)*68 + co];
      *(short8v*)(g3T + cb + kq*8) = v;
    }
  }

  // phase 2: a1, a2 (shared X, 2-deep X+B)
  {
    f32x4 a1[2][4], a2[2][4];
#pragma unroll
    for (int ft = 0; ft < 2; ++ft)
#pragma unroll
      for (int mf = 0; mf < 4; ++mf) { a1[ft][mf] = (f32x4)0.f; a2[ft][mf] = (f32x4)0.f; }

    short8v xa[2][4];
    short8v b1f[2][2], b2f[2][2];
#pragma unroll
    for (int mf = 0; mf < 4; ++mf) {
      size_t ro = ((size_t)b*M1 + m0 + mf*16 + ln)*Jp12 + qw*8;
      xa[0][mf] = *(const short8v*)(XT12 + ro);
    }
    {
      size_t ab = (((size_t)0*nIt12 + w*2)*64 + lane)*8;
      b1f[0][0] = *(const short8v*)(Apk1 + ab);
      b1f[0][1] = *(const short8v*)(Apk1 + ab + 512);
      b2f[0][0] = *(const short8v*)(Apk2 + ab);
      b2f[0][1] = *(const short8v*)(Apk2 + ab + 512);
    }
#pragma unroll
    for (int ks = 0; ks < KT12; ++ks) {
      if (ks + 1 < KT12) {
        int nx = (ks + 1) & 1;
#pragma unroll
        for (int mf = 0; mf < 4; ++mf) {
          size_t ro = ((size_t)b*M1 + m0 + mf*16 + ln)*Jp12 + (ks + 1)*32 + qw*8;
          xa[nx][mf] = *(const short8v*)(XT12 + ro);
        }
        size_t ab = (((size_t)(ks + 1)*nIt12 + w*2)*64 + lane)*8;
        b1f[nx][0] = *(const short8v*)(Apk1 + ab);
        b1f[nx][1] = *(const short8v*)(Apk1 + ab + 512);
        b2f[nx][0] = *(const short8v*)(Apk2 + ab);
        b2f[nx][1] = *(const short8v*)(Apk2 + ab + 512);
      }
      int cu = ks & 1;
#pragma unroll
      for (int mf = 0; mf < 4; ++mf) {
        a1[0][mf] = MFMA16(xa[cu][mf], b1f[cu][0], a1[0][mf], 0, 0, 0);
        a1[1][mf] = MFMA16(xa[cu][mf], b1f[cu][1], a1[1][mf], 0, 0, 0);
        a2[0][mf] = MFMA16(xa[cu][mf], b2f[cu][0], a2[0][mf], 0, 0, 0);
        a2[1][mf] = MFMA16(xa[cu][mf], b2f[cu][1], a2[1][mf], 0, 0, 0);
      }
    }
#pragma unroll
    for (int ft = 0; ft < 2; ++ft)
#pragma unroll
      for (int mf = 0; mf < 4; ++mf) {
        int irow = ft*16 + ln;
        int cc = mf*16 + qw*4;
        short4v v1, v2;
#pragma unroll
        for (int r = 0; r < 4; ++r) {
          v1[r] = f2bf(a1[ft][mf][r]);
          v2[r] = f2bf(a2[ft][mf][r]);
        }
        *(short4v*)(s1 + irow*68 + cc) = v1;
        *(short4v*)(s2 + irow*68 + cc) = v2;
      }
  }

  // channel phase
  f32x4 u2a[2][4], u5a[2][4];
#pragma unroll
  for (int fi = 0; fi < 2; ++fi)
#pragma unroll
    for (int ct = 0; ct < 4; ++ct) { u2a[fi][ct] = (f32x4)0.f; u5a[fi][ct] = (f32x4)0.f; }

#pragma unroll
  for (int ks = 0; ks < 2; ++ks) {
    short8v f1[2], f2[2], f3[2];
#pragma unroll
    for (int fi = 0; fi < 2; ++fi) {
      int irow = fi*16 + ln;
      f1[fi] = *(const short8v*)(s1 + irow*68 + ks*32 + qw*8);
      f2[fi] = *(const short8v*)(s2 + irow*68 + ks*32 + qw*8);
      f3[fi] = *(const short8v*)(s3 + irow*68 + ks*32 + qw*8);
    }
#pragma unroll
    for (int ct = 0; ct < 4; ++ct) {
      short8v b1 = *(const short8v*)(th1 + ((ct*2 + ks)*64 + lane)*8);
      short8v b2 = *(const short8v*)(th2 + ((ct*2 + ks)*64 + lane)*8);
      short8v b3 = *(const short8v*)(th3 + ((ct*2 + ks)*64 + lane)*8);
#pragma unroll
      for (int fi = 0; fi < 2; ++fi) {
        u2a[fi][ct] = MFMA16(f1[fi], b1, u2a[fi][ct], 0, 0, 0);
        u5a[fi][ct] = MFMA16(f2[fi], b2, u5a[fi][ct], 0, 0, 0);
        u5a[fi][ct] = MFMA16(f3[fi], b3, u5a[fi][ct], 0, 0, 0);
      }
    }
  }

#pragma unroll
  for (int kq = 0; kq < 4; ++kq) {
    int il = kq*8 + (lane >> 3);
    *(short8v*)(s3 + il*68 + (lane & 7)*8) = x0r[kq];
  }

  short* sg = s1;
#pragma unroll
  for (int fi = 0; fi < 2; ++fi)
#pragma unroll
    for (int ct = 0; ct < 4; ++ct) {
      int co = ct*16 + ln;
#pragma unroll
      for (int r = 0; r < 4; ++r) {
        int il = fi*16 + qw*4 + r;
        int i = w*32 + il;
        short g = 0;
        if (i < I) {
          float u2 = fmaxf(u2a[fi][ct][r], 0.f);
          float u5 = sigmoidf_(u5a[fi][ct][r]);
          float u6 = fmaxf(0.5f*(u2 + u5), 0.f);
          float x0 = bf2f(s3[il*68 + co]);
          g = f2bf(fmaxf(0.9f*u6 + 0.1f*x0, 0.f));
        }
        sg[il*68 + co] = g;
      }
    }

#pragma unroll
  for (int kq = 0; kq < 4; ++kq) {
    int il = kq*8 + (lane >> 3);
    int irow = w*32 + il;
    short8v v = *(const short8v*)(sg + il*68 + (lane & 7)*8);
    if (irow < I)
      *(short8v*)(uout + ((size_t)b*IpadO + irow)*M1 + t*64 + (lane & 7)*8) = v;
  }

  {
    int co = lane;
    size_t cb = ((size_t)b*M1 + t*64 + co)*IpadO + w*32;
#pragma unroll
    for (int kq = 0; kq < 4; ++kq) {
      short8v v;
#pragma unroll
      for (int ii = 0; ii < 8; ++ii) v[ii] = sg[(kq*8 + ii)*68 + co];
      *(short8v*)(umT + cb + kq*8) = v;
    }
  }
}

// ---------- layer-b kernel: 1-wave blocks, factored G2, shared-B phase ----------
__global__ __launch_bounds__(64, 1) void k_layer_b(
    const short* __restrict__ X2T,    // g3T m-major [b][M1][PA]
    const short* __restrict__ X3T,    // uaT_new m-major [b][M1][PA]
    const short* __restrict__ X1T,    // ubT m-major [b][M1][PB]
    const short* __restrict__ ApkS,   // A10pk, nIt=20
    const short* __restrict__ Apk1,   // A11pk, nIt=20
    const short* __restrict__ th1, const short* __restrict__ th2,
    const short* __restrict__ th3,
    const short* __restrict__ X00, short* __restrict__ uout,
    short* __restrict__ umT) {
  const int NW = 10, I = NB, IpadO = PB;
  __shared__ short sd[3][32*68];
  int lane = threadIdx.x & 63;
  int ln = lane & 15, qw = lane >> 4;

  int total = NW*30*BB;
  int d = blockIdx.x;
  int logical = (d & 7)*(total >> 3) + (d >> 3);
  int w = logical % NW;
  int rest = logical / NW;
  int mt = rest % 30;
  int b = rest / 30;

  int m0 = mt*64;
  int t = mt;

  short* s1 = sd[0];
  short* s2 = sd[1];
  short* s3 = sd[2];

  short8v x0r[4];
#pragma unroll
  for (int kq = 0; kq < 4; ++kq) {
    int il = kq*8 + (lane >> 3);
    int irow = w*32 + il;
    if (irow >= I) irow = I - 1;
    size_t ro = ((size_t)b*IpadO + irow)*M1 + t*64 + (lane & 7)*8;
    x0r[kq] = *(const short8v*)(X00 + ro);
  }

  // === phase 1: a2 = A10@g3T, a3 = A10@uaT (shared B), K=96 ===
  {
    f32x4 a2[2][4], a3[2][4];
#pragma unroll
    for (int ft = 0; ft < 2; ++ft)
#pragma unroll
      for (int mf = 0; mf < 4; ++mf) { a2[ft][mf] = (f32x4)0.f; a3[ft][mf] = (f32x4)0.f; }

    short8v x2[2][4], x3[2][4];
    short8v bf[2][2];
#pragma unroll
    for (int mf = 0; mf < 4; ++mf) {
      size_t ro = ((size_t)b*M1 + m0 + mf*16 + ln)*PA + qw*8;
      x2[0][mf] = *(const short8v*)(X2T + ro);
      x3[0][mf] = *(const short8v*)(X3T + ro);
    }
    {
      size_t ab = (((size_t)0*20 + w*2)*64 + lane)*8;
      bf[0][0] = *(const short8v*)(ApkS + ab);
      bf[0][1] = *(const short8v*)(ApkS + ab + 512);
    }
#pragma unroll
    for (int ks = 0; ks < 3; ++ks) {
      if (ks + 1 < 3) {
        int nx = (ks + 1) & 1;
#pragma unroll
        for (int mf = 0; mf < 4; ++mf) {
          size_t ro = ((size_t)b*M1 + m0 + mf*16 + ln)*PA + (ks + 1)*32 + qw*8;
          x2[nx][mf] = *(const short8v*)(X2T + ro);
          x3[nx][mf] = *(const short8v*)(X3T + ro);
        }
        size_t ab = (((size_t)(ks + 1)*20 + w*2)*64 + lane)*8;
        bf[nx][0] = *(const short8v*)(ApkS + ab);
        bf[nx][1] = *(const short8v*)(ApkS + ab + 512);
      }
      int cu = ks & 1;
#pragma unroll
      for (int mf = 0; mf < 4; ++mf) {
        a2[0][mf] = MFMA16(x2[cu][mf], bf[cu][0], a2[0][mf], 0, 0, 0);
        a2[1][mf] = MFMA16(x2[cu][mf], bf[cu][1], a2[1][mf], 0, 0, 0);
        a3[0][mf] = MFMA16(x3[cu][mf], bf[cu][0], a3[0][mf], 0, 0, 0);
        a3[1][mf] = MFMA16(x3[cu][mf], bf[cu][1], a3[1][mf], 0, 0, 0);
      }
    }
#pragma unroll
    for (int ft = 0; ft < 2; ++ft)
#pragma unroll
      for (int mf = 0; mf < 4; ++mf) {
        int irow = ft*16 + ln;
        int cc = mf*16 + qw*4;
        short4v v2, v3;
#pragma unroll
        for (int r = 0; r < 4; ++r) {
          v2[r] = f2bf(a2[ft][mf][r]);
          v3[r] = f2bf(a3[ft][mf][r]);
        }
        *(short4v*)(s2 + irow*68 + cc) = v2;
        *(short4v*)(s3 + irow*68 + cc) = v3;
      }
  }

  // === phase 2: a1 = A11 @ ubT (K=320, 10 iters, 2-deep X+B) ===
  {
    f32x4 a1[2][4];
#pragma unroll
    for (int ft = 0; ft < 2; ++ft)
#pragma unroll
      for (int mf = 0; mf < 4; ++mf) a1[ft][mf] = (f32x4)0.f;

    short8v xa[2][4];
    short8v b1f[2][2];
#pragma unroll
    for (int mf = 0; mf < 4; ++mf) {
      size_t ro = ((size_t)b*M1 + m0 + mf*16 + ln)*PB + qw*8;
      xa[0][mf] = *(const short8v*)(X1T + ro);
    }
    {
      size_t ab = (((size_t)0*20 + w*2)*64 + lane)*8;
      b1f[0][0] = *(const short8v*)(Apk1 + ab);
      b1f[0][1] = *(const short8v*)(Apk1 + ab + 512);
    }
#pragma unroll
    for (int ks = 0; ks < 10; ++ks) {
      if (ks + 1 < 10) {
        int nx = (ks + 1) & 1;
#pragma unroll
        for (int mf = 0; mf < 4; ++mf) {
          size_t ro = ((size_t)b*M1 + m0 + mf*16 + ln)*PB + (ks + 1)*32 + qw*8;
          xa[nx][mf] = *(const short8v*)(X1T + ro);
        }
        size_t ab = (((size_t)(ks + 1)*20 + w*2)*64 + lane)*8;
        b1f[nx][0] = *(const short8v*)(Apk1 + ab);
        b1f[nx][1] = *(const short8v*)(Apk1 + ab + 512);
      }
      int cu = ks & 1;
#pragma unroll
      for (int mf = 0; mf < 4; ++mf) {
        a1[0][mf] = MFMA16(xa[cu][mf], b1f[cu][0], a1[0][mf], 0, 0, 0);
        a1[1][mf] = MFMA16(xa[cu][mf], b1f[cu][1], a1[1][mf], 0, 0, 0);
      }
    }
#pragma unroll
    for (int ft = 0; ft < 2; ++ft)
#pragma unroll
      for (int mf = 0; mf < 4; ++mf) {
        int irow = ft*16 + ln;
        int cc = mf*16 + qw*4;
        short4v v1;
#pragma unroll
        for (int r = 0; r < 4; ++r) v1[r] = f2bf(a1[ft][mf][r]);
        *(short4v*)(s1 + irow*68 + cc) = v1;
      }
  }

  // --- channel phase ---
  f32x4 u2a[2][4], u5a[2][4];
#pragma unroll
  for (int fi = 0; fi < 2; ++fi)
#pragma unroll
    for (int ct = 0; ct < 4; ++ct) { u2a[fi][ct] = (f32x4)0.f; u5a[fi][ct] = (f32x4)0.f; }

#pragma unroll
  for (int ks = 0; ks < 2; ++ks) {
    short8v f1[2], f2[2], f3[2];
#pragma unroll
    for (int fi = 0; fi < 2; ++fi) {
      int irow = fi*16 + ln;
      f1[fi] = *(const short8v*)(s1 + irow*68 + ks*32 + qw*8);
      f2[fi] = *(const short8v*)(s2 + irow*68 + ks*32 + qw*8);
      f3[fi] = *(const short8v*)(s3 + irow*68 + ks*32 + qw*8);
    }
#pragma unroll
    for (int ct = 0; ct < 4; ++ct) {
      short8v b1 = *(const short8v*)(th1 + ((ct*2 + ks)*64 + lane)*8);
      short8v b2 = *(const short8v*)(th2 + ((ct*2 + ks)*64 + lane)*8);
      short8v b3 = *(const short8v*)(th3 + ((ct*2 + ks)*64 + lane)*8);
#pragma unroll
      for (int fi = 0; fi < 2; ++fi) {
        u2a[fi][ct] = MFMA16(f1[fi], b1, u2a[fi][ct], 0, 0, 0);
        u5a[fi][ct] = MFMA16(f2[fi], b2, u5a[fi][ct], 0, 0, 0);
        u5a[fi][ct] = MFMA16(f3[fi], b3, u5a[fi][ct], 0, 0, 0);
      }
    }
  }

  // --- park X00 in s3 ---
#pragma unroll
  for (int kq = 0; kq < 4; ++kq) {
    int il = kq*8 + (lane >> 3);
    *(short8v*)(s3 + il*68 + (lane & 7)*8) = x0r[kq];
  }

  // --- gating + residual -> sg ---
  short* sg = s1;
#pragma unroll
  for (int fi = 0; fi < 2; ++fi)
#pragma unroll
    for (int ct = 0; ct < 4; ++ct) {
      int co = ct*16 + ln;
#pragma unroll
      for (int r = 0; r < 4; ++r) {
        int il = fi*16 + qw*4 + r;
        int i = w*32 + il;
        short g = 0;
        if (i < I) {
          float u2 = fmaxf(u2a[fi][ct][r], 0.f);
          float u5 = sigmoidf_(u5a[fi][ct][r]);
          float u6 = fmaxf(0.5f*(u2 + u5), 0.f);
          float x0 = bf2f(s3[il*68 + co]);
          g = f2bf(fmaxf(0.9f*u6 + 0.1f*x0, 0.f));
        }
        sg[il*68 + co] = g;
      }
    }

  // --- node-major store ---
#pragma unroll
  for (int kq = 0; kq < 4; ++kq) {
    int il = kq*8 + (lane >> 3);
    int irow = w*32 + il;
    short8v v = *(const short8v*)(sg + il*68 + (lane & 7)*8);
    if (irow < I)
      *(short8v*)(uout + ((size_t)b*IpadO + irow)*M1 + t*64 + (lane & 7)*8) = v;
  }

  // --- m-major store ---
  {
    int co = lane;
    size_t cb = ((size_t)b*M1 + t*64 + co)*IpadO + w*32;
#pragma unroll
    for (int kq = 0; kq < 4; ++kq) {
      short8v v;
#pragma unroll
      for (int ii = 0; ii < 8; ++ii) v[ii] = sg[(kq*8 + ii)*68 + co];
      *(short8v*)(umT + cb + kq*8) = v;
    }
  }
}

// ---------- fused theta matmul + conv2 + gating -> d_out fp32 ----------
__global__ __launch_bounds__(256) void k_thconv2(const short* __restrict__ u0,
                                                 const short* __restrict__ u1,
                                                 const short* __restrict__ thetapk,
                                                 const short* __restrict__ W2pk,
                                                 const float* __restrict__ b12,
                                                 const float* __restrict__ bc2,
                                                 float* __restrict__ out) {
  __shared__ short lds[34*72];
  int tid = threadIdx.x, lane = tid & 63, wv = tid >> 6;
  int ln = lane & 15, qw = lane >> 4;
  int bn = blockIdx.x;
  int b = blockIdx.y;
  const short* u; int i, Ipad;
  if (bn < NA) { u = u0; i = bn; Ipad = PA; }
  else         { u = u1; i = bn - NA; Ipad = PB; }
  for (int z = tid; z < 4*72; z += 256) lds[30*72 + z] = 0;

  f32x4 ac[2];
  ac[0] = (f32x4)0.f; ac[1] = (f32x4)0.f;
  size_t ubase = ((size_t)b*Ipad + i)*M1;
#pragma unroll
  for (int ks = 0; ks < 2; ++ks) {
    short8v bm = *(const short8v*)(thetapk + ((wv*2 + ks)*64 + lane)*8);
#pragma unroll
    for (int tf = 0; tf < 2; ++tf) {
      short8v af = *(const short8v*)(u + ubase + (tf*16 + ln)*64 + ks*32 + qw*8);
      ac[tf] = MFMA16(af, bm, ac[tf], 0, 0, 0);
    }
  }
#pragma unroll
  for (int tf = 0; tf < 2; ++tf)
#pragma unroll
    for (int r = 0; r < 4; ++r) {
      int t = tf*16 + qw*4 + r;
      if (t < T1) lds[t*72 + wv*16 + ln] = f2bf(fmaxf(ac[tf][r], 0.f));
    }
  __syncthreads();

  f32x4 a3[2][3];
#pragma unroll
  for (int tf = 0; tf < 2; ++tf)
#pragma unroll
    for (int s = 0; s < 3; ++s) a3[tf][s] = (f32x4)0.f;
  for (int ks = 0; ks < 6; ++ks) {
    short8v af[2];
#pragma unroll
    for (int tf = 0; tf < 2; ++tf) {
      int m = (tf*16 + ln)*64 + ks*32 + qw*8;
      af[tf] = *(const short8v*)(lds + (m >> 6)*72 + (m & 63));
    }
#pragma unroll
    for (int s = 0; s < 3; ++s) {
      int ct = wv + s*4;
      short8v bm = *(const short8v*)(W2pk + ((ct*6 + ks)*64 + lane)*8);
#pragma unroll
      for (int tf = 0; tf < 2; ++tf)
        a3[tf][s] = MFMA16(af[tf], bm, a3[tf][s], 0, 0, 0);
    }
  }
  int co = wv*16 + ln;
  float btm = b12[co], bp = bc2[co], bq = bc2[64 + co];
#pragma unroll
  for (int tf = 0; tf < 2; ++tf)
#pragma unroll
    for (int r = 0; r < 4; ++r) {
      int t = tf*16 + qw*4 + r;
      if (t >= T2) continue;
      float tm = a3[tf][0][r] + btm;
      float p  = a3[tf][1][r] + bp;
      float q  = a3[tf][2][r] + bq;
      out[((size_t)(b*400 + bn)*T2 + t)*64 + co] = (p + tm)*sigmoidf_(q);
    }
}

// ---------- batchnorm ----------
__global__ __launch_bounds__(256) void k_bn_stats(const float* __restrict__ y,
                                                  float* __restrict__ stats) {
  int n = blockIdx.x;
  int tid = threadIdx.x;
  float s = 0.f, ss = 0.f;
  for (int b = 0; b < BB; ++b) {
    const float* p = y + ((size_t)(b*400 + n))*(T2*64);
    for (int i2 = tid; i2 < T2*64; i2 += 256) {
      float v = p[i2];
      s += v; ss += v*v;
    }
  }
  __shared__ float rs[4], rss[4];
  for (int off = 32; off > 0; off >>= 1) {
    s += __shfl_down(s, off);
    ss += __shfl_down(ss, off);
  }
  if ((tid & 63) == 0) { rs[tid >> 6] = s; rss[tid >> 6] = ss; }
  __syncthreads();
  if (tid == 0) {
    float S = rs[0] + rs[1] + rs[2] + rs[3];
    float SS = rss[0] + rss[1] + rss[2] + rss[3];
    float mean = S/28672.f;
    float var = SS/28672.f - mean*mean;
    stats[n] = mean;
    stats[400 + n] = rsqrtf(var + 1e-5f);
  }
}

__global__ void k_bn_apply(float* __restrict__ y, const float* __restrict__ stats,
                           const float* __restrict__ gamma, const float* __restrict__ beta) {
  int idx = blockIdx.x*blockDim.x + threadIdx.x;
  const int total = BB*400*T2*64/4;
  for (; idx < total; idx += gridDim.x*blockDim.x) {
    int e = idx*4;
    int n = (e/(T2*64)) % 400;
    float mean = stats[n];
    float g = gamma[n]*stats[400 + n];
    float bt = beta[n];
    float4 v = ((float4*)y)[idx];
    v.x = (v.x - mean)*g + bt;
    v.y = (v.y - mean)*g + bt;
    v.z = (v.z - mean)*g + bt;
    v.w = (v.w - mean)*g + bt;
    ((float4*)y)[idx] = v;
  }
}

// ---------- host launcher ----------
extern "C" void kernel_launch(void* const* d_in, const int* in_sizes, int n_in,
                              void* d_out, int out_size, void* d_ws, size_t ws_size,
                              hipStream_t stream) {
  const float* X     = (const float*)d_in[0];
  const float* A00   = (const float*)d_in[1];
  const float* A01   = (const float*)d_in[2];
  const float* A10   = (const float*)d_in[3];
  const float* A11   = (const float*)d_in[4];
  const float* w11   = (const float*)d_in[5];
  const float* b11   = (const float*)d_in[6];
  const float* wc1   = (const float*)d_in[7];
  const float* bc1   = (const float*)d_in[8];
  const float* g1t1  = (const float*)d_in[9];
  const float* g1t2  = (const float*)d_in[10];
  const float* g1t3  = (const float*)d_in[11];
  const float* g2t1  = (const float*)d_in[12];
  const float* g2t2  = (const float*)d_in[13];
  const float* g2t3  = (const float*)d_in[14];
  const float* theta = (const float*)d_in[15];
  const float* w12   = (const float*)d_in[16];
  const float* b12   = (const float*)d_in[17];
  const float* wc2   = (const float*)d_in[18];
  const float* bc2   = (const float*)d_in[19];
  const float* gamma = (const float*)d_in[20];
  const float* beta  = (const float*)d_in[21];

  // ---- workspace layout (bf16/short units) ----
  short* ws = (short*)d_ws;
  size_t o = 0;
  const size_t szA = (size_t)BB*PA*M1;
  const size_t szB = (size_t)BB*PB*M1;
  short* t1a  = ws + o; o += szA;
  short* t1b  = ws + o; o += szB;
  short* u0   = ws + o; o += szA;
  short* u1   = ws + o; o += szB;
  short* uaT0 = ws + o; o += szA;
  short* uaT1 = ws + o; o += szA;
  short* ubT0 = ws + o; o += szB;
  short* ubT1 = ws + o; o += szB;
  short* g3T  = ws + o; o += szA;
  short* A00pk = ws + o; o += 12288;
  short* Mapk  = ws + o; o += 12288;
  short* A01pk = ws + o; o += 40960;
  short* A10pk = ws + o; o += 30720;
  short* A11pk = ws + o; o += 102400;
  short* thpk    = ws + o; o += 122880;
  short* thetapk = ws + o; o += 4096;
  short* W2pk    = ws + o; o += 36864;
  o = (o + 7) & ~(size_t)7;
  float* fws = (float*)(ws + o);
  float* Ma    = fws;
  float* stats = Ma + 6561;
  float* W1t   = stats + 800;
  float* B1t   = W1t + 1152;

  // ---- prep ----
  k_prep_mm<<<26, 256, 0, stream>>>(A01, A10, Ma);
  k_pack_A<<<776, 256, 0, stream>>>(A00, A01, A10, A11, Ma,
                                    A00pk, Mapk, A01pk, A10pk, A11pk);
  k_pack_th<<<646, 256, 0, stream>>>(g1t1, g1t2, g1t3, g2t1, g2t2, g2t3, theta,
                                     w12, wc2, w11, wc1, b11, bc1,
                                     thpk, thetapk, W2pk, W1t, B1t);
  k_tconv1<<<BB*400, 192, 0, stream>>>(X, W1t, B1t, t1a, t1b);
  k_transpose<<<dim3(PA/64, 4, BB), 256, 0, stream>>>(t1a, uaT0, PA);
  k_transpose<<<dim3(PB/64, 4, BB), 256, 0, stream>>>(t1b, ubT0, PB);

  short* uaT[2] = {uaT0, uaT1};
  short* ubT[2] = {ubT0, ubT1};
  for (int l = 0; l < 5; ++l) {
    int pin = l & 1, pout = 1 - pin;
    const short* th = thpk + (size_t)(l*6)*4096;
    // layer-a: 1-wave blocks, NW=3 (32-i windows), grid 3*30*16 = 1440
    k_layer_a<3, 10><<<1440, 64, 0, stream>>>(
        uaT[pin], PA, ubT[pin], PB, A00pk, Mapk, 8, A01pk, 8,
        th + 0*4096, th + 1*4096, th + 2*4096, t1a, u0, uaT[pout], g3T,
        3, NA, PA);
    // layer-b: 1-wave blocks, NW=10, grid 10*30*16 = 4800
    k_layer_b<<<4800, 64, 0, stream>>>(
        g3T, uaT[pout], ubT[pin], A10pk, A11pk,
        th + 3*4096, th + 4*4096, th + 5*4096, t1b, u1, ubT[pout]);
  }

  // fused theta + conv2 + gating -> d_out fp32
  k_thconv2<<<dim3(400, BB), 256, 0, stream>>>(u0, u1, thetapk, W2pk, b12, bc2,
                                               (float*)d_out);
  // batchnorm in place
  k_bn_stats<<<400, 256, 0, stream>>>((float*)d_out, stats);
  k_bn_apply<<<2048, 256, 0, stream>>>((float*)d_out, stats, gamma, beta);
}

// Round 21
// 530.794 us; speedup vs baseline: 1.1124x; 1.0065x over previous
//
#include <hip/hip_runtime.h>

// HetSTGCNBlock round 21 = round 18/20 (best, 534us) + DEPTH-4 X+B pipeline
// in the two LONG phases (layer_a phase1 K=320, layer_b phase2 K=320).
// Theory: 2-deep covers only ~1 iter (~120cy) of the ~200-400cy L2 latency;
// 4-deep covers 3 iters (~360cy). Register cost +48 in phases where only one
// 64-AGPR acc set is live (phase-split context where the allocator
// cooperated at depth 2, unlike r13's all-accs-live attempt).
// Short 3-iter phases stay 2-deep. Everything else identical to r18.

typedef __attribute__((ext_vector_type(8))) short short8v;
typedef __attribute__((ext_vector_type(4))) short short4v;
typedef __attribute__((ext_vector_type(4))) float f32x4;

#define BB 16
#define NA 81
#define NB 319
#define PA 128
#define PB 320
#define M1 1920     // 30*64
#define T1 30
#define T2 28

#define MFMA16 __builtin_amdgcn_mfma_f32_16x16x32_bf16

__device__ __forceinline__ float sigmoidf_(float x){ return 1.0f/(1.0f+__expf(-x)); }
__device__ __forceinline__ short f2bf(float f){
  unsigned u = __float_as_uint(f);
  u += 0x7FFF + ((u>>16)&1);
  return (short)(u>>16);
}
__device__ __forceinline__ float bf2f(short s){
  return __uint_as_float(((unsigned)(unsigned short)s)<<16);
}

// ---------- prep: Ma = A01@A10 (81x81) fp32 ----------
__global__ __launch_bounds__(256) void k_prep_mm(const float* __restrict__ A01,
                                                 const float* __restrict__ A10,
                                                 float* __restrict__ Ma) {
  int idx = blockIdx.x*256 + threadIdx.x;
  if (idx >= NA*NA) return;
  int i = idx / NA, j = idx % NA;
  float a = 0.f;
  for (int k = 0; k < NB; ++k) a += A01[i*NB + k]*A10[k*NA + j];
  Ma[idx] = a;
}

// ---------- pack mixing matrices into B-frag order, bf16 ----------
__device__ __forceinline__ void packA_one(int f, const float* src, int I, int J,
                                          int ld, int nIt, short* dst) {
  int e = f & 7, l = (f >> 3) & 63, rest = f >> 9;
  int it = rest % nIt, jt = rest / nIt;
  int i = it*16 + (l & 15);
  int j = jt*32 + (l >> 4)*8 + e;
  float v = (i < I && j < J) ? src[i*ld + j] : 0.f;
  dst[f] = f2bf(v);
}

__global__ __launch_bounds__(256) void k_pack_A(
    const float* __restrict__ A00, const float* __restrict__ A01,
    const float* __restrict__ A10, const float* __restrict__ A11,
    const float* __restrict__ Ma,
    short* __restrict__ A00pk, short* __restrict__ Mapk,
    short* __restrict__ A01pk, short* __restrict__ A10pk,
    short* __restrict__ A11pk) {
  int idx = blockIdx.x*256 + threadIdx.x;
  if (idx < 12288)        { packA_one(idx, A00, NA, NA, NA, 8,  A00pk); return; }
  idx -= 12288;
  if (idx < 12288)        { packA_one(idx, Ma,  NA, NA, NA, 8,  Mapk);  return; }
  idx -= 12288;
  if (idx < 40960)        { packA_one(idx, A01, NA, NB, NB, 8,  A01pk); return; }
  idx -= 40960;
  if (idx < 30720)        { packA_one(idx, A10, NB, NA, NA, 20, A10pk); return; }
  idx -= 30720;
  if (idx < 102400)       { packA_one(idx, A11, NB, NB, NB, 20, A11pk); return; }
}

// ---------- pack th (30 mats), theta, conv2 weights; + tconv1 weights fp32 ----------
__global__ __launch_bounds__(256) void k_pack_th(
    const float* __restrict__ g1t1, const float* __restrict__ g1t2,
    const float* __restrict__ g1t3, const float* __restrict__ g2t1,
    const float* __restrict__ g2t2, const float* __restrict__ g2t3,
    const float* __restrict__ theta,
    const float* __restrict__ w12, const float* __restrict__ wc2,
    const float* __restrict__ w11, const float* __restrict__ wc1,
    const float* __restrict__ b11, const float* __restrict__ bc1,
    short* __restrict__ thpk, short* __restrict__ thetapk,
    short* __restrict__ W2pk, float* __restrict__ W1t, float* __restrict__ B1t) {
  int idx = blockIdx.x*256 + threadIdx.x;
  if (idx < 122880) {
    int mat = idx / 4096, rem = idx % 4096;
    int ct = rem / 1024, ks = (rem / 512) & 1, l = (rem >> 3) & 63, e = rem & 7;
    int ci = ks*32 + (l >> 4)*8 + e, co = ct*16 + (l & 15);
    int layer = mat / 6, which = mat % 6;
    const float* src = which == 0 ? g1t1 : which == 1 ? g1t2 : which == 2 ? g1t3
                     : which == 3 ? g2t1 : which == 4 ? g2t2 : g2t3;
    thpk[idx] = f2bf(src[layer*4096 + ci*64 + co]);
    return;
  }
  idx -= 122880;
  if (idx < 4096) {
    int ct = idx / 1024, ks = (idx / 512) & 1, l = (idx >> 3) & 63, e = idx & 7;
    int ci = ks*32 + (l >> 4)*8 + e, co = ct*16 + (l & 15);
    thetapk[idx] = f2bf(theta[ci*64 + co]);
    return;
  }
  idx -= 4096;
  if (idx < 36864) {
    int ct = idx / 3072, rem = idx % 3072;
    int ks = rem / 512, l = (rem >> 3) & 63, e = rem & 7;
    int kap = ks*32 + (l >> 4)*8 + e;
    int k = kap >> 6, ci = kap & 63;
    int cc = ct*16 + (l & 15);
    float v = (cc < 64) ? w12[cc*192 + ci*3 + k] : wc2[(cc - 64)*192 + ci*3 + k];
    W2pk[idx] = f2bf(v);
    return;
  }
  idx -= 36864;
  if (idx < 1152) {
    int kk = idx / 192, cc = idx % 192;
    int k = kk >> 1, ci = kk & 1;
    W1t[idx] = (cc < 64) ? w11[cc*6 + ci*3 + k] : wc1[(cc - 64)*6 + ci*3 + k];
    return;
  }
  idx -= 1152;
  if (idx < 192) { B1t[idx] = (idx < 64) ? b11[idx] : bc1[idx - 64]; return; }
}

// ---------- temporal conv 1 (Cin=2), gated -> node-major bf16 ----------
__global__ __launch_bounds__(192) void k_tconv1(const float* __restrict__ X,
                                                const float* __restrict__ W1t,
                                                const float* __restrict__ B1t,
                                                short* __restrict__ t1a,
                                                short* __restrict__ t1b) {
  __shared__ float xl[64];
  __shared__ float wl[6*192];
  __shared__ float bl[192];
  __shared__ float ol[T1*192];
  int bn = blockIdx.x;
  int b = bn / 400, n = bn % 400;
  int tid = threadIdx.x;
  if (tid < 64) xl[tid] = X[(size_t)bn*64 + tid];
  for (int i2 = tid; i2 < 6*192; i2 += 192) wl[i2] = W1t[i2];
  bl[tid] = B1t[tid];
  __syncthreads();
  float acc[T1];
  float bias = bl[tid];
#pragma unroll
  for (int t = 0; t < T1; ++t) acc[t] = bias;
#pragma unroll
  for (int kk = 0; kk < 6; ++kk) {
    float w = wl[kk*192 + tid];
    int k = kk >> 1, ci = kk & 1;
#pragma unroll
    for (int t = 0; t < T1; ++t) acc[t] += xl[(t + k)*2 + ci]*w;
  }
#pragma unroll
  for (int t = 0; t < T1; ++t) ol[t*192 + tid] = acc[t];
  __syncthreads();
  short* dst = (n < NA) ? (t1a + ((size_t)b*PA + n)*M1)
                        : (t1b + ((size_t)b*PB + (n - NA))*M1);
  for (int p = tid; p < T1*64; p += 192) {
    int t = p >> 6, c = p & 63;
    float v = (ol[t*192 + 64 + c] + ol[t*192 + c])*sigmoidf_(ol[t*192 + 128 + c]);
    dst[p] = f2bf(v);
  }
}

// ---------- transpose: node-major -> m-major (initial only) ----------
__global__ __launch_bounds__(256) void k_transpose(const short* __restrict__ src,
                                                   short* __restrict__ dst, int Ipad) {
  int lane = threadIdx.x & 63, wv = threadIdx.x >> 6;
  int n = blockIdx.x*64 + lane;
  int b = blockIdx.z;
  const short* sp = src + ((size_t)b*Ipad + n)*M1;
  int mbase = (blockIdx.y*4 + wv)*120;
  for (int k = 0; k < 120; k += 8) {
    int m = mbase + k;
    short8v v = *(const short8v*)(sp + m);
#pragma unroll
    for (int e = 0; e < 8; ++e)
      dst[((size_t)b*M1 + m + e)*Ipad + n] = v[e];
  }
}

// ---------- layer-a kernel: 1-wave blocks, depth-4 long phase, g3T export ----------
template<int KT12, int KT3>
__global__ __launch_bounds__(64, 1) void k_layer_a(
    const short* __restrict__ XT12, int Jp12,
    const short* __restrict__ XT3, int Jp3,
    const short* __restrict__ Apk1, const short* __restrict__ Apk2, int nIt12,
    const short* __restrict__ Apk3, int nIt3,
    const short* __restrict__ th1, const short* __restrict__ th2,
    const short* __restrict__ th3,
    const short* __restrict__ X00, short* __restrict__ uout,
    short* __restrict__ umT, short* __restrict__ g3T,
    int NW, int I, int IpadO) {
  __shared__ short sd[3][32*68];
  int lane = threadIdx.x & 63;
  int ln = lane & 15, qw = lane >> 4;

  int total = NW*30*BB;
  int d = blockIdx.x;
  int logical = (d & 7)*(total >> 3) + (d >> 3);
  int w = logical % NW;
  int rest = logical / NW;
  int mt = rest % 30;
  int b = rest / 30;

  int m0 = mt*64;
  int t = mt;

  short* s1 = sd[0];
  short* s2 = sd[1];
  short* s3 = sd[2];

  short8v x0r[4];
#pragma unroll
  for (int kq = 0; kq < 4; ++kq) {
    int il = kq*8 + (lane >> 3);
    int irow = w*32 + il;
    if (irow >= I) irow = I - 1;
    size_t ro = ((size_t)b*IpadO + irow)*M1 + t*64 + (lane & 7)*8;
    x0r[kq] = *(const short8v*)(X00 + ro);
  }

  // === phase 1: a3 = Apk3 @ XT3 (DEPTH-4 X+B), spill s3, export g3T ===
  {
    f32x4 a3[2][4];
#pragma unroll
    for (int ft = 0; ft < 2; ++ft)
#pragma unroll
      for (int mf = 0; mf < 4; ++mf) a3[ft][mf] = (f32x4)0.f;

    short8v xa[4][4];
    short8v b3f[4][2];
#pragma unroll
    for (int p = 0; p < 3; ++p) {
      if (p < KT3) {
#pragma unroll
        for (int mf = 0; mf < 4; ++mf) {
          size_t ro = ((size_t)b*M1 + m0 + mf*16 + ln)*Jp3 + p*32 + qw*8;
          xa[p][mf] = *(const short8v*)(XT3 + ro);
        }
        size_t ab = (((size_t)p*nIt3 + w*2)*64 + lane)*8;
        b3f[p][0] = *(const short8v*)(Apk3 + ab);
        b3f[p][1] = *(const short8v*)(Apk3 + ab + 512);
      }
    }
#pragma unroll
    for (int ks = 0; ks < KT3; ++ks) {
      if (ks + 3 < KT3) {
        int nx = (ks + 3) & 3;
#pragma unroll
        for (int mf = 0; mf < 4; ++mf) {
          size_t ro = ((size_t)b*M1 + m0 + mf*16 + ln)*Jp3 + (ks + 3)*32 + qw*8;
          xa[nx][mf] = *(const short8v*)(XT3 + ro);
        }
        size_t ab = (((size_t)(ks + 3)*nIt3 + w*2)*64 + lane)*8;
        b3f[nx][0] = *(const short8v*)(Apk3 + ab);
        b3f[nx][1] = *(const short8v*)(Apk3 + ab + 512);
      }
      int cu = ks & 3;
#pragma unroll
      for (int mf = 0; mf < 4; ++mf) {
        a3[0][mf] = MFMA16(xa[cu][mf], b3f[cu][0], a3[0][mf], 0, 0, 0);
        a3[1][mf] = MFMA16(xa[cu][mf], b3f[cu][1], a3[1][mf], 0, 0, 0);
      }
    }
#pragma unroll
    for (int ft = 0; ft < 2; ++ft)
#pragma unroll
      for (int mf = 0; mf < 4; ++mf) {
        int irow = ft*16 + ln;
        int cc = mf*16 + qw*4;
        short4v v3;
#pragma unroll
        for (int r = 0; r < 4; ++r) v3[r] = f2bf(a3[ft][mf][r]);
        *(short4v*)(s3 + irow*68 + cc) = v3;
      }
  }
  {
    int co = lane;
    size_t cb = ((size_t)b*M1 + t*64 + co)*IpadO + w*32;
#pragma unroll
    for (int kq = 0; kq < 4; ++kq) {
      short8v v;
#pragma unroll
      for (int ii = 0; ii < 8; ++ii) v[ii] = s3[(kq*8 + ii)*68 + co];
      *(short8v*)(g3T + cb + kq*8) = v;
    }
  }

  // === phase 2: a1, a2 (shared X, 2-deep X+B; KT12=3 short) ===
  {
    f32x4 a1[2][4], a2[2][4];
#pragma unroll
    for (int ft = 0; ft < 2; ++ft)
#pragma unroll
      for (int mf = 0; mf < 4; ++mf) { a1[ft][mf] = (f32x4)0.f; a2[ft][mf] = (f32x4)0.f; }

    short8v xa[2][4];
    short8v b1f[2][2], b2f[2][2];
#pragma unroll
    for (int mf = 0; mf < 4; ++mf) {
      size_t ro = ((size_t)b*M1 + m0 + mf*16 + ln)*Jp12 + qw*8;
      xa[0][mf] = *(const short8v*)(XT12 + ro);
    }
    {
      size_t ab = (((size_t)0*nIt12 + w*2)*64 + lane)*8;
      b1f[0][0] = *(const short8v*)(Apk1 + ab);
      b1f[0][1] = *(const short8v*)(Apk1 + ab + 512);
      b2f[0][0] = *(const short8v*)(Apk2 + ab);
      b2f[0][1] = *(const short8v*)(Apk2 + ab + 512);
    }
#pragma unroll
    for (int ks = 0; ks < KT12; ++ks) {
      if (ks + 1 < KT12) {
        int nx = (ks + 1) & 1;
#pragma unroll
        for (int mf = 0; mf < 4; ++mf) {
          size_t ro = ((size_t)b*M1 + m0 + mf*16 + ln)*Jp12 + (ks + 1)*32 + qw*8;
          xa[nx][mf] = *(const short8v*)(XT12 + ro);
        }
        size_t ab = (((size_t)(ks + 1)*nIt12 + w*2)*64 + lane)*8;
        b1f[nx][0] = *(const short8v*)(Apk1 + ab);
        b1f[nx][1] = *(const short8v*)(Apk1 + ab + 512);
        b2f[nx][0] = *(const short8v*)(Apk2 + ab);
        b2f[nx][1] = *(const short8v*)(Apk2 + ab + 512);
      }
      int cu = ks & 1;
#pragma unroll
      for (int mf = 0; mf < 4; ++mf) {
        a1[0][mf] = MFMA16(xa[cu][mf], b1f[cu][0], a1[0][mf], 0, 0, 0);
        a1[1][mf] = MFMA16(xa[cu][mf], b1f[cu][1], a1[1][mf], 0, 0, 0);
        a2[0][mf] = MFMA16(xa[cu][mf], b2f[cu][0], a2[0][mf], 0, 0, 0);
        a2[1][mf] = MFMA16(xa[cu][mf], b2f[cu][1], a2[1][mf], 0, 0, 0);
      }
    }
#pragma unroll
    for (int ft = 0; ft < 2; ++ft)
#pragma unroll
      for (int mf = 0; mf < 4; ++mf) {
        int irow = ft*16 + ln;
        int cc = mf*16 + qw*4;
        short4v v1, v2;
#pragma unroll
        for (int r = 0; r < 4; ++r) {
          v1[r] = f2bf(a1[ft][mf][r]);
          v2[r] = f2bf(a2[ft][mf][r]);
        }
        *(short4v*)(s1 + irow*68 + cc) = v1;
        *(short4v*)(s2 + irow*68 + cc) = v2;
      }
  }

  // channel phase
  f32x4 u2a[2][4], u5a[2][4];
#pragma unroll
  for (int fi = 0; fi < 2; ++fi)
#pragma unroll
    for (int ct = 0; ct < 4; ++ct) { u2a[fi][ct] = (f32x4)0.f; u5a[fi][ct] = (f32x4)0.f; }

#pragma unroll
  for (int ks = 0; ks < 2; ++ks) {
    short8v f1[2], f2[2], f3[2];
#pragma unroll
    for (int fi = 0; fi < 2; ++fi) {
      int irow = fi*16 + ln;
      f1[fi] = *(const short8v*)(s1 + irow*68 + ks*32 + qw*8);
      f2[fi] = *(const short8v*)(s2 + irow*68 + ks*32 + qw*8);
      f3[fi] = *(const short8v*)(s3 + irow*68 + ks*32 + qw*8);
    }
#pragma unroll
    for (int ct = 0; ct < 4; ++ct) {
      short8v b1 = *(const short8v*)(th1 + ((ct*2 + ks)*64 + lane)*8);
      short8v b2 = *(const short8v*)(th2 + ((ct*2 + ks)*64 + lane)*8);
      short8v b3 = *(const short8v*)(th3 + ((ct*2 + ks)*64 + lane)*8);
#pragma unroll
      for (int fi = 0; fi < 2; ++fi) {
        u2a[fi][ct] = MFMA16(f1[fi], b1, u2a[fi][ct], 0, 0, 0);
        u5a[fi][ct] = MFMA16(f2[fi], b2, u5a[fi][ct], 0, 0, 0);
        u5a[fi][ct] = MFMA16(f3[fi], b3, u5a[fi][ct], 0, 0, 0);
      }
    }
  }

#pragma unroll
  for (int kq = 0; kq < 4; ++kq) {
    int il = kq*8 + (lane >> 3);
    *(short8v*)(s3 + il*68 + (lane & 7)*8) = x0r[kq];
  }

  short* sg = s1;
#pragma unroll
  for (int fi = 0; fi < 2; ++fi)
#pragma unroll
    for (int ct = 0; ct < 4; ++ct) {
      int co = ct*16 + ln;
#pragma unroll
      for (int r = 0; r < 4; ++r) {
        int il = fi*16 + qw*4 + r;
        int i = w*32 + il;
        short g = 0;
        if (i < I) {
          float u2 = fmaxf(u2a[fi][ct][r], 0.f);
          float u5 = sigmoidf_(u5a[fi][ct][r]);
          float u6 = fmaxf(0.5f*(u2 + u5), 0.f);
          float x0 = bf2f(s3[il*68 + co]);
          g = f2bf(fmaxf(0.9f*u6 + 0.1f*x0, 0.f));
        }
        sg[il*68 + co] = g;
      }
    }

#pragma unroll
  for (int kq = 0; kq < 4; ++kq) {
    int il = kq*8 + (lane >> 3);
    int irow = w*32 + il;
    short8v v = *(const short8v*)(sg + il*68 + (lane & 7)*8);
    if (irow < I)
      *(short8v*)(uout + ((size_t)b*IpadO + irow)*M1 + t*64 + (lane & 7)*8) = v;
  }

  {
    int co = lane;
    size_t cb = ((size_t)b*M1 + t*64 + co)*IpadO + w*32;
#pragma unroll
    for (int kq = 0; kq < 4; ++kq) {
      short8v v;
#pragma unroll
      for (int ii = 0; ii < 8; ++ii) v[ii] = sg[(kq*8 + ii)*68 + co];
      *(short8v*)(umT + cb + kq*8) = v;
    }
  }
}

// ---------- layer-b kernel: 1-wave blocks, factored G2, depth-4 long phase ----------
__global__ __launch_bounds__(64, 1) void k_layer_b(
    const short* __restrict__ X2T,    // g3T m-major [b][M1][PA]
    const short* __restrict__ X3T,    // uaT_new m-major [b][M1][PA]
    const short* __restrict__ X1T,    // ubT m-major [b][M1][PB]
    const short* __restrict__ ApkS,   // A10pk, nIt=20
    const short* __restrict__ Apk1,   // A11pk, nIt=20
    const short* __restrict__ th1, const short* __restrict__ th2,
    const short* __restrict__ th3,
    const short* __restrict__ X00, short* __restrict__ uout,
    short* __restrict__ umT) {
  const int NW = 10, I = NB, IpadO = PB;
  __shared__ short sd[3][32*68];
  int lane = threadIdx.x & 63;
  int ln = lane & 15, qw = lane >> 4;

  int total = NW*30*BB;
  int d = blockIdx.x;
  int logical = (d & 7)*(total >> 3) + (d >> 3);
  int w = logical % NW;
  int rest = logical / NW;
  int mt = rest % 30;
  int b = rest / 30;

  int m0 = mt*64;
  int t = mt;

  short* s1 = sd[0];
  short* s2 = sd[1];
  short* s3 = sd[2];

  short8v x0r[4];
#pragma unroll
  for (int kq = 0; kq < 4; ++kq) {
    int il = kq*8 + (lane >> 3);
    int irow = w*32 + il;
    if (irow >= I) irow = I - 1;
    size_t ro = ((size_t)b*IpadO + irow)*M1 + t*64 + (lane & 7)*8;
    x0r[kq] = *(const short8v*)(X00 + ro);
  }

  // === phase 1: a2 = A10@g3T, a3 = A10@uaT (shared B), K=96, 2-deep ===
  {
    f32x4 a2[2][4], a3[2][4];
#pragma unroll
    for (int ft = 0; ft < 2; ++ft)
#pragma unroll
      for (int mf = 0; mf < 4; ++mf) { a2[ft][mf] = (f32x4)0.f; a3[ft][mf] = (f32x4)0.f; }

    short8v x2[2][4], x3[2][4];
    short8v bf[2][2];
#pragma unroll
    for (int mf = 0; mf < 4; ++mf) {
      size_t ro = ((size_t)b*M1 + m0 + mf*16 + ln)*PA + qw*8;
      x2[0][mf] = *(const short8v*)(X2T + ro);
      x3[0][mf] = *(const short8v*)(X3T + ro);
    }
    {
      size_t ab = (((size_t)0*20 + w*2)*64 + lane)*8;
      bf[0][0] = *(const short8v*)(ApkS + ab);
      bf[0][1] = *(const short8v*)(ApkS + ab + 512);
    }
#pragma unroll
    for (int ks = 0; ks < 3; ++ks) {
      if (ks + 1 < 3) {
        int nx = (ks + 1) & 1;
#pragma unroll
        for (int mf = 0; mf < 4; ++mf) {
          size_t ro = ((size_t)b*M1 + m0 + mf*16 + ln)*PA + (ks + 1)*32 + qw*8;
          x2[nx][mf] = *(const short8v*)(X2T + ro);
          x3[nx][mf] = *(const short8v*)(X3T + ro);
        }
        size_t ab = (((size_t)(ks + 1)*20 + w*2)*64 + lane)*8;
        bf[nx][0] = *(const short8v*)(ApkS + ab);
        bf[nx][1] = *(const short8v*)(ApkS + ab + 512);
      }
      int cu = ks & 1;
#pragma unroll
      for (int mf = 0; mf < 4; ++mf) {
        a2[0][mf] = MFMA16(x2[cu][mf], bf[cu][0], a2[0][mf], 0, 0, 0);
        a2[1][mf] = MFMA16(x2[cu][mf], bf[cu][1], a2[1][mf], 0, 0, 0);
        a3[0][mf] = MFMA16(x3[cu][mf], bf[cu][0], a3[0][mf], 0, 0, 0);
        a3[1][mf] = MFMA16(x3[cu][mf], bf[cu][1], a3[1][mf], 0, 0, 0);
      }
    }
#pragma unroll
    for (int ft = 0; ft < 2; ++ft)
#pragma unroll
      for (int mf = 0; mf < 4; ++mf) {
        int irow = ft*16 + ln;
        int cc = mf*16 + qw*4;
        short4v v2, v3;
#pragma unroll
        for (int r = 0; r < 4; ++r) {
          v2[r] = f2bf(a2[ft][mf][r]);
          v3[r] = f2bf(a3[ft][mf][r]);
        }
        *(short4v*)(s2 + irow*68 + cc) = v2;
        *(short4v*)(s3 + irow*68 + cc) = v3;
      }
  }

  // === phase 2: a1 = A11 @ ubT (K=320, 10 iters, DEPTH-4 X+B) ===
  {
    f32x4 a1[2][4];
#pragma unroll
    for (int ft = 0; ft < 2; ++ft)
#pragma unroll
      for (int mf = 0; mf < 4; ++mf) a1[ft][mf] = (f32x4)0.f;

    short8v xa[4][4];
    short8v b1f[4][2];
#pragma unroll
    for (int p = 0; p < 3; ++p) {
#pragma unroll
      for (int mf = 0; mf < 4; ++mf) {
        size_t ro = ((size_t)b*M1 + m0 + mf*16 + ln)*PB + p*32 + qw*8;
        xa[p][mf] = *(const short8v*)(X1T + ro);
      }
      size_t ab = (((size_t)p*20 + w*2)*64 + lane)*8;
      b1f[p][0] = *(const short8v*)(Apk1 + ab);
      b1f[p][1] = *(const short8v*)(Apk1 + ab + 512);
    }
#pragma unroll
    for (int ks = 0; ks < 10; ++ks) {
      if (ks + 3 < 10) {
        int nx = (ks + 3) & 3;
#pragma unroll
        for (int mf = 0; mf < 4; ++mf) {
          size_t ro = ((size_t)b*M1 + m0 + mf*16 + ln)*PB + (ks + 3)*32 + qw*8;
          xa[nx][mf] = *(const short8v*)(X1T + ro);
        }
        size_t ab = (((size_t)(ks + 3)*20 + w*2)*64 + lane)*8;
        b1f[nx][0] = *(const short8v*)(Apk1 + ab);
        b1f[nx][1] = *(const short8v*)(Apk1 + ab + 512);
      }
      int cu = ks & 3;
#pragma unroll
      for (int mf = 0; mf < 4; ++mf) {
        a1[0][mf] = MFMA16(xa[cu][mf], b1f[cu][0], a1[0][mf], 0, 0, 0);
        a1[1][mf] = MFMA16(xa[cu][mf], b1f[cu][1], a1[1][mf], 0, 0, 0);
      }
    }
#pragma unroll
    for (int ft = 0; ft < 2; ++ft)
#pragma unroll
      for (int mf = 0; mf < 4; ++mf) {
        int irow = ft*16 + ln;
        int cc = mf*16 + qw*4;
        short4v v1;
#pragma unroll
        for (int r = 0; r < 4; ++r) v1[r] = f2bf(a1[ft][mf][r]);
        *(short4v*)(s1 + irow*68 + cc) = v1;
      }
  }

  // --- channel phase ---
  f32x4 u2a[2][4], u5a[2][4];
#pragma unroll
  for (int fi = 0; fi < 2; ++fi)
#pragma unroll
    for (int ct = 0; ct < 4; ++ct) { u2a[fi][ct] = (f32x4)0.f; u5a[fi][ct] = (f32x4)0.f; }

#pragma unroll
  for (int ks = 0; ks < 2; ++ks) {
    short8v f1[2], f2[2], f3[2];
#pragma unroll
    for (int fi = 0; fi < 2; ++fi) {
      int irow = fi*16 + ln;
      f1[fi] = *(const short8v*)(s1 + irow*68 + ks*32 + qw*8);
      f2[fi] = *(const short8v*)(s2 + irow*68 + ks*32 + qw*8);
      f3[fi] = *(const short8v*)(s3 + irow*68 + ks*32 + qw*8);
    }
#pragma unroll
    for (int ct = 0; ct < 4; ++ct) {
      short8v b1 = *(const short8v*)(th1 + ((ct*2 + ks)*64 + lane)*8);
      short8v b2 = *(const short8v*)(th2 + ((ct*2 + ks)*64 + lane)*8);
      short8v b3 = *(const short8v*)(th3 + ((ct*2 + ks)*64 + lane)*8);
#pragma unroll
      for (int fi = 0; fi < 2; ++fi) {
        u2a[fi][ct] = MFMA16(f1[fi], b1, u2a[fi][ct], 0, 0, 0);
        u5a[fi][ct] = MFMA16(f2[fi], b2, u5a[fi][ct], 0, 0, 0);
        u5a[fi][ct] = MFMA16(f3[fi], b3, u5a[fi][ct], 0, 0, 0);
      }
    }
  }

  // --- park X00 in s3 ---
#pragma unroll
  for (int kq = 0; kq < 4; ++kq) {
    int il = kq*8 + (lane >> 3);
    *(short8v*)(s3 + il*68 + (lane & 7)*8) = x0r[kq];
  }

  // --- gating + residual -> sg ---
  short* sg = s1;
#pragma unroll
  for (int fi = 0; fi < 2; ++fi)
#pragma unroll
    for (int ct = 0; ct < 4; ++ct) {
      int co = ct*16 + ln;
#pragma unroll
      for (int r = 0; r < 4; ++r) {
        int il = fi*16 + qw*4 + r;
        int i = w*32 + il;
        short g = 0;
        if (i < I) {
          float u2 = fmaxf(u2a[fi][ct][r], 0.f);
          float u5 = sigmoidf_(u5a[fi][ct][r]);
          float u6 = fmaxf(0.5f*(u2 + u5), 0.f);
          float x0 = bf2f(s3[il*68 + co]);
          g = f2bf(fmaxf(0.9f*u6 + 0.1f*x0, 0.f));
        }
        sg[il*68 + co] = g;
      }
    }

  // --- node-major store ---
#pragma unroll
  for (int kq = 0; kq < 4; ++kq) {
    int il = kq*8 + (lane >> 3);
    int irow = w*32 + il;
    short8v v = *(const short8v*)(sg + il*68 + (lane & 7)*8);
    if (irow < I)
      *(short8v*)(uout + ((size_t)b*IpadO + irow)*M1 + t*64 + (lane & 7)*8) = v;
  }

  // --- m-major store ---
  {
    int co = lane;
    size_t cb = ((size_t)b*M1 + t*64 + co)*IpadO + w*32;
#pragma unroll
    for (int kq = 0; kq < 4; ++kq) {
      short8v v;
#pragma unroll
      for (int ii = 0; ii < 8; ++ii) v[ii] = sg[(kq*8 + ii)*68 + co];
      *(short8v*)(umT + cb + kq*8) = v;
    }
  }
}

// ---------- fused theta matmul + conv2 + gating -> d_out fp32 ----------
__global__ __launch_bounds__(256) void k_thconv2(const short* __restrict__ u0,
                                                 const short* __restrict__ u1,
                                                 const short* __restrict__ thetapk,
                                                 const short* __restrict__ W2pk,
                                                 const float* __restrict__ b12,
                                                 const float* __restrict__ bc2,
                                                 float* __restrict__ out) {
  __shared__ short lds[34*72];
  int tid = threadIdx.x, lane = tid & 63, wv = tid >> 6;
  int ln = lane & 15, qw = lane >> 4;
  int bn = blockIdx.x;
  int b = blockIdx.y;
  const short* u; int i, Ipad;
  if (bn < NA) { u = u0; i = bn; Ipad = PA; }
  else         { u = u1; i = bn - NA; Ipad = PB; }
  for (int z = tid; z < 4*72; z += 256) lds[30*72 + z] = 0;

  f32x4 ac[2];
  ac[0] = (f32x4)0.f; ac[1] = (f32x4)0.f;
  size_t ubase = ((size_t)b*Ipad + i)*M1;
#pragma unroll
  for (int ks = 0; ks < 2; ++ks) {
    short8v bm = *(const short8v*)(thetapk + ((wv*2 + ks)*64 + lane)*8);
#pragma unroll
    for (int tf = 0; tf < 2; ++tf) {
      short8v af = *(const short8v*)(u + ubase + (tf*16 + ln)*64 + ks*32 + qw*8);
      ac[tf] = MFMA16(af, bm, ac[tf], 0, 0, 0);
    }
  }
#pragma unroll
  for (int tf = 0; tf < 2; ++tf)
#pragma unroll
    for (int r = 0; r < 4; ++r) {
      int t = tf*16 + qw*4 + r;
      if (t < T1) lds[t*72 + wv*16 + ln] = f2bf(fmaxf(ac[tf][r], 0.f));
    }
  __syncthreads();

  f32x4 a3[2][3];
#pragma unroll
  for (int tf = 0; tf < 2; ++tf)
#pragma unroll
    for (int s = 0; s < 3; ++s) a3[tf][s] = (f32x4)0.f;
  for (int ks = 0; ks < 6; ++ks) {
    short8v af[2];
#pragma unroll
    for (int tf = 0; tf < 2; ++tf) {
      int m = (tf*16 + ln)*64 + ks*32 + qw*8;
      af[tf] = *(const short8v*)(lds + (m >> 6)*72 + (m & 63));
    }
#pragma unroll
    for (int s = 0; s < 3; ++s) {
      int ct = wv + s*4;
      short8v bm = *(const short8v*)(W2pk + ((ct*6 + ks)*64 + lane)*8);
#pragma unroll
      for (int tf = 0; tf < 2; ++tf)
        a3[tf][s] = MFMA16(af[tf], bm, a3[tf][s], 0, 0, 0);
    }
  }
  int co = wv*16 + ln;
  float btm = b12[co], bp = bc2[co], bq = bc2[64 + co];
#pragma unroll
  for (int tf = 0; tf < 2; ++tf)
#pragma unroll
    for (int r = 0; r < 4; ++r) {
      int t = tf*16 + qw*4 + r;
      if (t >= T2) continue;
      float tm = a3[tf][0][r] + btm;
      float p  = a3[tf][1][r] + bp;
      float q  = a3[tf][2][r] + bq;
      out[((size_t)(b*400 + bn)*T2 + t)*64 + co] = (p + tm)*sigmoidf_(q);
    }
}

// ---------- batchnorm ----------
__global__ __launch_bounds__(256) void k_bn_stats(const float* __restrict__ y,
                                                  float* __restrict__ stats) {
  int n = blockIdx.x;
  int tid = threadIdx.x;
  float s = 0.f, ss = 0.f;
  for (int b = 0; b < BB; ++b) {
    const float* p = y + ((size_t)(b*400 + n))*(T2*64);
    for (int i2 = tid; i2 < T2*64; i2 += 256) {
      float v = p[i2];
      s += v; ss += v*v;
    }
  }
  __shared__ float rs[4], rss[4];
  for (int off = 32; off > 0; off >>= 1) {
    s += __shfl_down(s, off);
    ss += __shfl_down(ss, off);
  }
  if ((tid & 63) == 0) { rs[tid >> 6] = s; rss[tid >> 6] = ss; }
  __syncthreads();
  if (tid == 0) {
    float S = rs[0] + rs[1] + rs[2] + rs[3];
    float SS = rss[0] + rss[1] + rss[2] + rss[3];
    float mean = S/28672.f;
    float var = SS/28672.f - mean*mean;
    stats[n] = mean;
    stats[400 + n] = rsqrtf(var + 1e-5f);
  }
}

__global__ void k_bn_apply(float* __restrict__ y, const float* __restrict__ stats,
                           const float* __restrict__ gamma, const float* __restrict__ beta) {
  int idx = blockIdx.x*blockDim.x + threadIdx.x;
  const int total = BB*400*T2*64/4;
  for (; idx < total; idx += gridDim.x*blockDim.x) {
    int e = idx*4;
    int n = (e/(T2*64)) % 400;
    float mean = stats[n];
    float g = gamma[n]*stats[400 + n];
    float bt = beta[n];
    float4 v = ((float4*)y)[idx];
    v.x = (v.x - mean)*g + bt;
    v.y = (v.y - mean)*g + bt;
    v.z = (v.z - mean)*g + bt;
    v.w = (v.w - mean)*g + bt;
    ((float4*)y)[idx] = v;
  }
}

// ---------- host launcher ----------
extern "C" void kernel_launch(void* const* d_in, const int* in_sizes, int n_in,
                              void* d_out, int out_size, void* d_ws, size_t ws_size,
                              hipStream_t stream) {
  const float* X     = (const float*)d_in[0];
  const float* A00   = (const float*)d_in[1];
  const float* A01   = (const float*)d_in[2];
  const float* A10   = (const float*)d_in[3];
  const float* A11   = (const float*)d_in[4];
  const float* w11   = (const float*)d_in[5];
  const float* b11   = (const float*)d_in[6];
  const float* wc1   = (const float*)d_in[7];
  const float* bc1   = (const float*)d_in[8];
  const float* g1t1  = (const float*)d_in[9];
  const float* g1t2  = (const float*)d_in[10];
  const float* g1t3  = (const float*)d_in[11];
  const float* g2t1  = (const float*)d_in[12];
  const float* g2t2  = (const float*)d_in[13];
  const float* g2t3  = (const float*)d_in[14];
  const float* theta = (const float*)d_in[15];
  const float* w12   = (const float*)d_in[16];
  const float* b12   = (const float*)d_in[17];
  const float* wc2   = (const float*)d_in[18];
  const float* bc2   = (const float*)d_in[19];
  const float* gamma = (const float*)d_in[20];
  const float* beta  = (const float*)d_in[21];

  // ---- workspace layout (bf16/short units) ----
  short* ws = (short*)d_ws;
  size_t o = 0;
  const size_t szA = (size_t)BB*PA*M1;
  const size_t szB = (size_t)BB*PB*M1;
  short* t1a  = ws + o; o += szA;
  short* t1b  = ws + o; o += szB;
  short* u0   = ws + o; o += szA;
  short* u1   = ws + o; o += szB;
  short* uaT0 = ws + o; o += szA;
  short* uaT1 = ws + o; o += szA;
  short* ubT0 = ws + o; o += szB;
  short* ubT1 = ws + o; o += szB;
  short* g3T  = ws + o; o += szA;
  short* A00pk = ws + o; o += 12288;
  short* Mapk  = ws + o; o += 12288;
  short* A01pk = ws + o; o += 40960;
  short* A10pk = ws + o; o += 30720;
  short* A11pk = ws + o; o += 102400;
  short* thpk    = ws + o; o += 122880;
  short* thetapk = ws + o; o += 4096;
  short* W2pk    = ws + o; o += 36864;
  o = (o + 7) & ~(size_t)7;
  float* fws = (float*)(ws + o);
  float* Ma    = fws;
  float* stats = Ma + 6561;
  float* W1t   = stats + 800;
  float* B1t   = W1t + 1152;

  // ---- prep ----
  k_prep_mm<<<26, 256, 0, stream>>>(A01, A10, Ma);
  k_pack_A<<<776, 256, 0, stream>>>(A00, A01, A10, A11, Ma,
                                    A00pk, Mapk, A01pk, A10pk, A11pk);
  k_pack_th<<<646, 256, 0, stream>>>(g1t1, g1t2, g1t3, g2t1, g2t2, g2t3, theta,
                                     w12, wc2, w11, wc1, b11, bc1,
                                     thpk, thetapk, W2pk, W1t, B1t);
  k_tconv1<<<BB*400, 192, 0, stream>>>(X, W1t, B1t, t1a, t1b);
  k_transpose<<<dim3(PA/64, 4, BB), 256, 0, stream>>>(t1a, uaT0, PA);
  k_transpose<<<dim3(PB/64, 4, BB), 256, 0, stream>>>(t1b, ubT0, PB);

  short* uaT[2] = {uaT0, uaT1};
  short* ubT[2] = {ubT0, ubT1};
  for (int l = 0; l < 5; ++l) {
    int pin = l & 1, pout = 1 - pin;
    const short* th = thpk + (size_t)(l*6)*4096;
    // layer-a: 1-wave blocks, NW=3 (32-i windows), grid 3*30*16 = 1440
    k_layer_a<3, 10><<<1440, 64, 0, stream>>>(
        uaT[pin], PA, ubT[pin], PB, A00pk, Mapk, 8, A01pk, 8,
        th + 0*4096, th + 1*4096, th + 2*4096, t1a, u0, uaT[pout], g3T,
        3, NA, PA);
    // layer-b: 1-wave blocks, NW=10, grid 10*30*16 = 4800
    k_layer_b<<<4800, 64, 0, stream>>>(
        g3T, uaT[pout], ubT[pin], A10pk, A11pk,
        th + 3*4096, th + 4*4096, th + 5*4096, t1b, u1, ubT[pout]);
  }

  // fused theta + conv2 + gating -> d_out fp32
  k_thconv2<<<dim3(400, BB), 256, 0, stream>>>(u0, u1, thetapk, W2pk, b12, bc2,
                                               (float*)d_out);
  // batchnorm in place
  k_bn_stats<<<400, 256, 0, stream>>>((float*)d_out, stats);
  k_bn_apply<<<2048, 256, 0, stream>>>((float*)d_out, stats, gamma, beta);
}